// Round 6
// baseline (874.108 us; speedup 1.0000x reference)
//
#include <hip/hip_runtime.h>
#include <stdint.h>

// SAGE_876173328847: 2-layer bipartite SAGEConv (mean agg) + log_softmax.
// N0=200000, N1=100000, N2=20000, E1=1.6M, E2=320K, D_IN=128, D_H=256, D_OUT=64.
//
// R1: atomic scatter -> CSR build + gather (3309 -> 667 us).
// R2/R3: bf16 heavy path + MFMA GEMMs (667 -> 547 us).
// R4: fused mega-kernel, h1 lives only in LDS (547 -> 472 us).
// R5: kill sub-word scattered-store HBM write amplification:
//     (a) mega epilogue: LDS-stage output tiles, coalesced int4 stores
//         (WRITE 207 MB -> ~25 MB);
//     (b) CSR place via 2-pass bucketed counting sort (dense cursor-packed
//         pair writes + LDS-cursor place, WRITE 108 MB -> ~23 MB);
//     (c) deg via per-bucket LDS counting (drops global scattered hist).

#define CN0 200000
#define CN1 100000
#define CN2 20000
#define CE1 1600000
#define CE2 320000
#define CD_IN 128
#define CD_H 256
#define CD_OUT 64

#define BCAP 2560          // bucket capacity (mean ~2046, 11 sigma margin)
#define NB1 782            // ceil(N1/128)
#define NB2 157            // ceil(N2/128)

typedef __bf16 bf16x8 __attribute__((ext_vector_type(8)));
typedef float f32x4 __attribute__((ext_vector_type(4)));
typedef uint16_t u16x4 __attribute__((ext_vector_type(4)));

__device__ inline uint16_t f2bf(float f) {
  uint32_t u = __float_as_uint(f);
  return (uint16_t)((u + 0x7fffu + ((u >> 16) & 1u)) >> 16);
}

// ---------------- dtype converts ----------------
__global__ __launch_bounds__(256) void cvt_f32_bf16_v4(
    const float* __restrict__ in, uint16_t* __restrict__ out, int n4) {
  int i = blockIdx.x * 256 + threadIdx.x;
  if (i >= n4) return;
  float4 v = reinterpret_cast<const float4*>(in)[i];
  u16x4 o = {f2bf(v.x), f2bf(v.y), f2bf(v.z), f2bf(v.w)};
  reinterpret_cast<u16x4*>(out)[i] = o;
}

__global__ __launch_bounds__(256) void cvt_wcat(
    const float* __restrict__ Wl, const float* __restrict__ Wr,
    uint16_t* __restrict__ out) {
  int i = blockIdx.x * 256 + threadIdx.x;  // 65536 total
  int j = i >> 8, k = i & 255;
  float v = (k < 128) ? Wl[j * 128 + k] : Wr[j * 128 + (k - 128)];
  out[i] = f2bf(v);
}

__global__ __launch_bounds__(256) void cvt_small(
    const float* __restrict__ in, uint16_t* __restrict__ out, int n) {
  int i = blockIdx.x * 256 + threadIdx.x;
  if (i < n) out[i] = f2bf(in[i]);
}

// ---------------- bucketed counting sort ----------------
// pass A: scatter (src,dst) pairs into fixed-cap buckets (dst>>7).
// Cursor allocation packs writes densely within each bucket -> full-line fills.
__global__ __launch_bounds__(256) void sage_bucket(
    const int* __restrict__ src, const int* __restrict__ dst,
    int* __restrict__ bcur, uint2* __restrict__ pairs, int E) {
  int e = blockIdx.x * 256 + threadIdx.x;
  if (e >= E) return;
  int s = src[e];
  int d = dst[e];
  int b = d >> 7;
  int p = atomicAdd(&bcur[b], 1);
  if (p < BCAP) pairs[(size_t)b * BCAP + p] = uint2{(unsigned)s, (unsigned)d};
}

// per-bucket degree count via LDS counters (dense deg writes)
__global__ __launch_bounds__(256) void sage_bdeg(
    const uint2* __restrict__ pairs, const int* __restrict__ bcur,
    int* __restrict__ deg, int ndst) {
  __shared__ int cnt[128];
  int b = blockIdx.x;
  int t = threadIdx.x;
  if (t < 128) cnt[t] = 0;
  __syncthreads();
  int n = min(bcur[b], BCAP);
  const uint2* pb = pairs + (size_t)b * BCAP;
  for (int i = t; i < n; i += 256) atomicAdd(&cnt[pb[i].y & 127], 1);
  __syncthreads();
  int d = (b << 7) + t;
  if (t < 128 && d < ndst) deg[d] = cnt[t];
}

// pass B: place srcs into CSR esrc using LDS cursors.
// Each block's esrc write window is ~8 KB contiguous -> dense writebacks.
__global__ __launch_bounds__(256) void sage_bplace(
    const uint2* __restrict__ pairs, const int* __restrict__ bcur,
    const int* __restrict__ R, int* __restrict__ esrc, int ndst) {
  __shared__ int curs[128];
  int b = blockIdx.x;
  int t = threadIdx.x;
  int based = b << 7;
  if (t < 128) {
    int d = based + t;
    curs[t] = (d < ndst) ? R[d] : 0;
  }
  __syncthreads();
  int n = min(bcur[b], BCAP);
  const uint2* pb = pairs + (size_t)b * BCAP;
  for (int i = t; i < n; i += 256) {
    uint2 pr = pb[i];
    int p = atomicAdd(&curs[pr.y & 127], 1);
    esrc[p] = (int)pr.x;
  }
}

// ---------------- scan (R from deg) ----------------
__global__ __launch_bounds__(256) void sage_scan_local(
    const int* __restrict__ deg, int* __restrict__ R, int* __restrict__ part, int N) {
  __shared__ int sm[256];
  int t = threadIdx.x;
  int base = blockIdx.x * 512;
  int i0 = base + 2 * t, i1 = base + 2 * t + 1;
  int a = (i0 < N) ? deg[i0] : 0;
  int b = (i1 < N) ? deg[i1] : 0;
  int s = a + b;
  sm[t] = s;
  __syncthreads();
#pragma unroll
  for (int off = 1; off < 256; off <<= 1) {
    int v = (t >= off) ? sm[t - off] : 0;
    __syncthreads();
    sm[t] += v;
    __syncthreads();
  }
  int excl = sm[t] - s;
  if (i0 < N) R[i0] = excl;
  if (i1 < N) R[i1] = excl + a;
  if (t == 255) part[blockIdx.x] = sm[255];
}

__global__ __launch_bounds__(256) void sage_scan_part(int* __restrict__ part, int B) {
  __shared__ int sm[256];
  int t = threadIdx.x;
  int v = (t < B) ? part[t] : 0;
  sm[t] = v;
  __syncthreads();
#pragma unroll
  for (int off = 1; off < 256; off <<= 1) {
    int u = (t >= off) ? sm[t - off] : 0;
    __syncthreads();
    sm[t] += u;
    __syncthreads();
  }
  if (t < B) part[t] = sm[t] - v;
}

__global__ __launch_bounds__(256) void sage_addback(
    int* __restrict__ R, const int* __restrict__ part, int N) {
  int i = blockIdx.x * 256 + threadIdx.x;
  if (i < N) R[i] += part[i >> 9];
}

// ---------------- gather-mean (bf16 in), layer 1: 64 lanes/dst ----------------
__global__ __launch_bounds__(256) void sage_gather1(
    const uint16_t* __restrict__ xbf, const int* __restrict__ esrc,
    const int* __restrict__ R, const int* __restrict__ deg,
    uint16_t* __restrict__ agg) {
  int d = blockIdx.x * 4 + (threadIdx.x >> 6);
  int c = threadIdx.x & 63;
  if (d >= CN1) return;
  int start = R[d], n = deg[d];
  const uint32_t* xw = reinterpret_cast<const uint32_t*>(xbf);
  float a0 = 0.f, a1 = 0.f;
  int i = 0;
  for (; i + 4 <= n; i += 4) {
    int s0 = esrc[start + i + 0];
    int s1 = esrc[start + i + 1];
    int s2 = esrc[start + i + 2];
    int s3 = esrc[start + i + 3];
    uint32_t v0 = xw[(size_t)s0 * 64 + c];
    uint32_t v1 = xw[(size_t)s1 * 64 + c];
    uint32_t v2 = xw[(size_t)s2 * 64 + c];
    uint32_t v3 = xw[(size_t)s3 * 64 + c];
    a0 += __uint_as_float(v0 << 16) + __uint_as_float(v1 << 16) +
          __uint_as_float(v2 << 16) + __uint_as_float(v3 << 16);
    a1 += __uint_as_float(v0 & 0xffff0000u) + __uint_as_float(v1 & 0xffff0000u) +
          __uint_as_float(v2 & 0xffff0000u) + __uint_as_float(v3 & 0xffff0000u);
  }
  for (; i < n; ++i) {
    uint32_t v = xw[(size_t)esrc[start + i] * 64 + c];
    a0 += __uint_as_float(v << 16);
    a1 += __uint_as_float(v & 0xffff0000u);
  }
  float inv = 1.0f / fmaxf((float)n, 1.0f);
  a0 *= inv; a1 *= inv;
  uint32_t packed = (uint32_t)f2bf(a0) | ((uint32_t)f2bf(a1) << 16);
  reinterpret_cast<uint32_t*>(agg)[(size_t)d * 64 + c] = packed;
}

// ---------------- gather-mean (bf16 in), layer 2: 32 lanes/dst, f32 out ----
__global__ __launch_bounds__(256) void sage_gather2(
    const uint16_t* __restrict__ t2, const int* __restrict__ esrc,
    const int* __restrict__ R, const int* __restrict__ deg,
    float* __restrict__ agg) {
  int d = blockIdx.x * 8 + (threadIdx.x >> 5);
  int c = threadIdx.x & 31;
  if (d >= CN2) return;
  int start = R[d], n = deg[d];
  const uint32_t* tw = reinterpret_cast<const uint32_t*>(t2);
  float a0 = 0.f, a1 = 0.f;
  int i = 0;
  for (; i + 4 <= n; i += 4) {
    int s0 = esrc[start + i + 0];
    int s1 = esrc[start + i + 1];
    int s2 = esrc[start + i + 2];
    int s3 = esrc[start + i + 3];
    uint32_t v0 = tw[(size_t)s0 * 32 + c];
    uint32_t v1 = tw[(size_t)s1 * 32 + c];
    uint32_t v2 = tw[(size_t)s2 * 32 + c];
    uint32_t v3 = tw[(size_t)s3 * 32 + c];
    a0 += __uint_as_float(v0 << 16) + __uint_as_float(v1 << 16) +
          __uint_as_float(v2 << 16) + __uint_as_float(v3 << 16);
    a1 += __uint_as_float(v0 & 0xffff0000u) + __uint_as_float(v1 & 0xffff0000u) +
          __uint_as_float(v2 & 0xffff0000u) + __uint_as_float(v3 & 0xffff0000u);
  }
  for (; i < n; ++i) {
    uint32_t v = tw[(size_t)esrc[start + i] * 32 + c];
    a0 += __uint_as_float(v << 16);
    a1 += __uint_as_float(v & 0xffff0000u);
  }
  float inv = 1.0f / fmaxf((float)n, 1.0f);
  float2 o = {a0 * inv, a1 * inv};
  reinterpret_cast<float2*>(agg)[(size_t)d * 32 + c] = o;
}

// ---------------- MEGA kernel ----------------
// Per 64-row block (4 waves; wave w owns rows w*16..w*16+15):
//   phase 1: h1_lds[64][256] = relu([agg|x] @ Wcat^T + b1)   (bf16, LDS only)
//   phase 2: acc2 = h1 @ W2cat^T  (cols 0..63 -> t2, 64..127 -> out partial)
//   epilogue: stage both tiles in LDS (h1s dead), coalesced int4 stores.
__global__ __launch_bounds__(256) void sage_mega(
    const uint16_t* __restrict__ agg, const uint16_t* __restrict__ xbf,
    const uint16_t* __restrict__ wcat, const uint16_t* __restrict__ w2cat,
    const float* __restrict__ bias, uint16_t* __restrict__ t2,
    float* __restrict__ outp) {
  __shared__ uint16_t lds[39936];
  uint16_t* As  = lds;            // [64][72]
  uint16_t* Ws  = lds + 4608;     // [256][72]  (phase 2: W2s [128][72])
  uint16_t* h1s = lds + 23040;    // [64][264]; epilogue: t2s[64][64]u16 + outs[64][64]f32

  const int tid = threadIdx.x;
  const int w = tid >> 6;
  const int lane = tid & 63;
  const int lr = lane >> 4;
  const int lc = lane & 15;
  const int row0 = blockIdx.x * 64;

  // ---- phase 1 ----
  f32x4 acc1[16];
#pragma unroll
  for (int n = 0; n < 16; ++n) acc1[n] = (f32x4)0.0f;

  for (int t = 0; t < 4; ++t) {
    const int k0 = t * 64;
    const uint16_t* Asrc = (t < 2) ? agg : xbf;
    const int koff = (t < 2) ? k0 : k0 - 128;

    int4 av[2];
#pragma unroll
    for (int i = 0; i < 2; ++i) {
      int q = tid + 256 * i;
      int r = q >> 3, c = q & 7;
      int rg = row0 + r;
      rg = rg < CN1 ? rg : CN1 - 1;
      av[i] = *reinterpret_cast<const int4*>(Asrc + (size_t)rg * CD_IN + koff + c * 8);
    }
    int4 wv[8];
#pragma unroll
    for (int i = 0; i < 8; ++i) {
      int q = tid + 256 * i;
      int r = q >> 3, c = q & 7;
      wv[i] = *reinterpret_cast<const int4*>(wcat + (size_t)r * 256 + k0 + c * 8);
    }
    __syncthreads();
#pragma unroll
    for (int i = 0; i < 2; ++i) {
      int q = tid + 256 * i;
      int r = q >> 3, c = q & 7;
      *reinterpret_cast<int4*>(&As[r * 72 + c * 8]) = av[i];
    }
#pragma unroll
    for (int i = 0; i < 8; ++i) {
      int q = tid + 256 * i;
      int r = q >> 3, c = q & 7;
      *reinterpret_cast<int4*>(&Ws[r * 72 + c * 8]) = wv[i];
    }
    __syncthreads();

#pragma unroll
    for (int ks = 0; ks < 2; ++ks) {
      const int kb = ks * 32 + lr * 8;
      bf16x8 af = *reinterpret_cast<const bf16x8*>(&As[(w * 16 + lc) * 72 + kb]);
#pragma unroll
      for (int n = 0; n < 16; ++n) {
        bf16x8 bfv = *reinterpret_cast<const bf16x8*>(&Ws[(n * 16 + lc) * 72 + kb]);
        acc1[n] = __builtin_amdgcn_mfma_f32_16x16x32_bf16(af, bfv, acc1[n], 0, 0, 0);
      }
    }
    __syncthreads();
  }

  // epilogue 1: bias + relu -> bf16 -> h1s
#pragma unroll
  for (int n = 0; n < 16; ++n) {
    float bb = bias[n * 16 + lc];
#pragma unroll
    for (int i = 0; i < 4; ++i) {
      float v = fmaxf(acc1[n][i] + bb, 0.0f);
      h1s[(w * 16 + lr * 4 + i) * 264 + n * 16 + lc] = f2bf(v);
    }
  }

  // ---- phase 2 ----
  f32x4 acc2[8];
#pragma unroll
  for (int n = 0; n < 8; ++n) acc2[n] = (f32x4)0.0f;

  for (int t = 0; t < 4; ++t) {
    const int k0 = t * 64;
    int4 wv[4];
#pragma unroll
    for (int i = 0; i < 4; ++i) {
      int q = tid + 256 * i;
      int r = q >> 3, c = q & 7;
      wv[i] = *reinterpret_cast<const int4*>(w2cat + (size_t)r * 256 + k0 + c * 8);
    }
    __syncthreads();
#pragma unroll
    for (int i = 0; i < 4; ++i) {
      int q = tid + 256 * i;
      int r = q >> 3, c = q & 7;
      *reinterpret_cast<int4*>(&Ws[r * 72 + c * 8]) = wv[i];
    }
    __syncthreads();

#pragma unroll
    for (int ks = 0; ks < 2; ++ks) {
      const int kb = ks * 32 + lr * 8;
      bf16x8 af = *reinterpret_cast<const bf16x8*>(&h1s[(w * 16 + lc) * 264 + k0 + kb]);
#pragma unroll
      for (int n = 0; n < 8; ++n) {
        bf16x8 bfv = *reinterpret_cast<const bf16x8*>(&Ws[(n * 16 + lc) * 72 + kb]);
        acc2[n] = __builtin_amdgcn_mfma_f32_16x16x32_bf16(af, bfv, acc2[n], 0, 0, 0);
      }
    }
  }

  // ---- epilogue 2: LDS-stage output tiles, then coalesced stores ----
  __syncthreads();                        // all phase-2 reads of h1s/Ws done
  uint16_t* t2s = h1s;                    // [64][64] u16 (8 KB)
  float* outs = (float*)(h1s + 4096);     // [64][64] f32 (16 KB)
#pragma unroll
  for (int i = 0; i < 4; ++i) {
    int rl = w * 16 + lr * 4 + i;
#pragma unroll
    for (int n = 0; n < 4; ++n) t2s[rl * 64 + n * 16 + lc] = f2bf(acc2[n][i]);
#pragma unroll
    for (int n = 0; n < 4; ++n) outs[rl * 64 + n * 16 + lc] = acc2[n + 4][i];
  }
  __syncthreads();
  // t2 tile: 64 rows x 128 B = 512 int4, 2 per thread
#pragma unroll
  for (int i = 0; i < 2; ++i) {
    int q = tid + 256 * i;
    int r = q >> 3, c = q & 7;
    int rg = row0 + r;
    if (rg < CN1)
      reinterpret_cast<int4*>(t2 + (size_t)rg * 64)[c] =
          *reinterpret_cast<const int4*>(&t2s[r * 64 + c * 8]);
  }
  // out tile: 64 rows x 256 B = 1024 int4, 4 per thread (rows < N2 only)
  if (row0 < CN2) {
#pragma unroll
    for (int i = 0; i < 4; ++i) {
      int q = tid + 256 * i;
      int r = q >> 4, c = q & 15;
      int rg = row0 + r;
      if (rg < CN2)
        reinterpret_cast<int4*>(outp + (size_t)rg * 64)[c] =
            *reinterpret_cast<const int4*>(&outs[r * 64 + c * 4]);
    }
  }
}

// ---------------- finalize: out = log_softmax(out + agg2 + b2) ----------------
__global__ __launch_bounds__(256) void sage_finalize(
    const float* __restrict__ agg2, const float* __restrict__ b,
    float* __restrict__ out) {
  int row = blockIdx.x * 4 + (threadIdx.x >> 6);
  int lane = threadIdx.x & 63;
  if (row >= CN2) return;
  size_t o = (size_t)row * CD_OUT + lane;
  float v = out[o] + agg2[o] + b[lane];
  float m = v;
#pragma unroll
  for (int d = 32; d > 0; d >>= 1) m = fmaxf(m, __shfl_xor(m, d));
  float e = expf(v - m);
  float s = e;
#pragma unroll
  for (int d = 32; d > 0; d >>= 1) s += __shfl_xor(s, d);
  out[o] = v - m - logf(s);
}

extern "C" void kernel_launch(void* const* d_in, const int* in_sizes, int n_in,
                              void* d_out, int out_size, void* d_ws, size_t ws_size,
                              hipStream_t stream) {
  const float* x    = (const float*)d_in[0];
  const int* src1   = (const int*)d_in[1];
  const int* dst1   = (const int*)d_in[2];
  const int* src2   = (const int*)d_in[3];
  const int* dst2   = (const int*)d_in[4];
  const float* W_l1 = (const float*)d_in[5];
  const float* b_l1 = (const float*)d_in[6];
  const float* W_r1 = (const float*)d_in[7];
  const float* W_l2 = (const float*)d_in[8];
  const float* b_l2 = (const float*)d_in[9];
  const float* W_r2 = (const float*)d_in[10];
  float* out = (float*)d_out;
  char* base = (char*)d_ws;

  // ---- workspace layout (bytes), total ~122.8 MB ----
  uint16_t* x_bf  = (uint16_t*)base;                       // 51.2 MB
  uint16_t* t2_bf = (uint16_t*)(base + 51200000);          // 12.8 MB
  uint2* pairs1   = (uint2*)(base + 64000000);             // 16.02 MB (NB1*BCAP*8)
  uint2* pairs2   = (uint2*)(base + 80015360);             // 3.22 MB  (NB2*BCAP*8)
  uint16_t* agg_bf= (uint16_t*)(base + 83230720);          // 25.6 MB
  float* agg2     = (float*)(base + 108830720);            // 5.12 MB
  int* deg1 = (int*)(base + 113950720);                    // 400 KB
  int* R1   = (int*)(base + 114350720);                    // 400 KB
  int* esrc1= (int*)(base + 114750720);                    // 6.4 MB
  int* deg2 = (int*)(base + 121150720);                    // 80 KB
  int* R2   = (int*)(base + 121230720);                    // 80 KB
  int* esrc2= (int*)(base + 121310720);                    // 1.28 MB
  char* misc = base + 122590720;
  int* part1 = (int*)misc;                                 // 1 KB
  int* part2 = (int*)(misc + 1024);                        // 1 KB
  int* bcur1 = (int*)(misc + 2048);                        // 3200 B (NB1 ints)
  int* bcur2 = (int*)(misc + 5248);                        // 640 B  (NB2 ints)
  uint16_t* wcat  = (uint16_t*)(misc + 5888);              // 128 KB, 16B aligned
  uint16_t* w2cat = wcat + 65536;                          // 64 KB

  if (ws_size < 123000000u) return;

  const int B1 = (CN1 + 511) / 512;  // 196
  const int B2 = (CN2 + 511) / 512;  // 40

  // ---- converts ----
  cvt_f32_bf16_v4<<<(CN0 * CD_IN / 4 + 255) / 256, 256, 0, stream>>>(x, x_bf, CN0 * CD_IN / 4);
  cvt_wcat<<<256, 256, 0, stream>>>(W_l1, W_r1, wcat);
  cvt_small<<<64, 256, 0, stream>>>(W_l2, w2cat, CD_OUT * CD_H);
  cvt_small<<<64, 256, 0, stream>>>(W_r2, w2cat + 16384, CD_OUT * CD_H);

  // ---- zero bucket cursors (contiguous: bcur1|bcur2) ----
  hipMemsetAsync(bcur1, 0, 3840, stream);

  // ---- layer 1: bucketed CSR + gather ----
  sage_bucket<<<(CE1 + 255) / 256, 256, 0, stream>>>(src1, dst1, bcur1, pairs1, CE1);
  sage_bdeg<<<NB1, 256, 0, stream>>>(pairs1, bcur1, deg1, CN1);
  sage_scan_local<<<B1, 256, 0, stream>>>(deg1, R1, part1, CN1);
  sage_scan_part<<<1, 256, 0, stream>>>(part1, B1);
  sage_addback<<<(CN1 + 255) / 256, 256, 0, stream>>>(R1, part1, CN1);
  sage_bplace<<<NB1, 256, 0, stream>>>(pairs1, bcur1, R1, esrc1, CN1);
  sage_gather1<<<(CN1 + 3) / 4, 256, 0, stream>>>(x_bf, esrc1, R1, deg1, agg_bf);

  // ---- mega: h1 in LDS; writes t2 + out-partial ----
  sage_mega<<<(CN1 + 63) / 64, 256, 0, stream>>>(
      agg_bf, x_bf, wcat, w2cat, b_l1, t2_bf, out);

  // ---- layer 2: bucketed CSR + gather ----
  sage_bucket<<<(CE2 + 255) / 256, 256, 0, stream>>>(src2, dst2, bcur2, pairs2, CE2);
  sage_bdeg<<<NB2, 256, 0, stream>>>(pairs2, bcur2, deg2, CN2);
  sage_scan_local<<<B2, 256, 0, stream>>>(deg2, R2, part2, CN2);
  sage_scan_part<<<1, 256, 0, stream>>>(part2, B2);
  sage_addback<<<(CN2 + 255) / 256, 256, 0, stream>>>(R2, part2, CN2);
  sage_bplace<<<NB2, 256, 0, stream>>>(pairs2, bcur2, R2, esrc2, CN2);
  sage_gather2<<<(CN2 + 7) / 8, 256, 0, stream>>>(t2_bf, esrc2, R2, deg2, agg2);

  // ---- finalize ----
  sage_finalize<<<(CN2 + 3) / 4, 256, 0, stream>>>(agg2, b_l2, out);
}

// Round 7
// 366.092 us; speedup vs baseline: 2.3877x; 2.3877x over previous
//
#include <hip/hip_runtime.h>
#include <stdint.h>

// SAGE_876173328847: 2-layer bipartite SAGEConv (mean agg) + log_softmax.
// N0=200000, N1=100000, N2=20000, E1=1.6M, E2=320K, D_IN=128, D_H=256, D_OUT=64.
//
// R1: atomic scatter -> CSR build + gather (3309 -> 667 us).
// R2/R3: bf16 heavy path + MFMA GEMMs (667 -> 547 us).
// R4: fused mega-kernel, h1 lives only in LDS (547 -> 472 us).
// R5: LDS-staged coalesced mega epilogue (kept).
// R6: contended-cursor bucket sort REGRESSED (377 us: 2046-way same-address
//     atomic serialization @ ~184 ns each). R7: scan-based multi-split --
//     deterministic offsets via block-histogram + scan, ZERO global atomics,
//     each output line written by one block/XCD (full-line writebacks).

#define CN0 200000
#define CN1 100000
#define CN2 20000
#define CE1 1600000
#define CE2 320000
#define CD_IN 128
#define CD_H 256
#define CD_OUT 64

// multi-split geometry: bucket = dst >> 9 (512 dsts per bucket)
#define NBK1 196          // ceil(N1/512)
#define NBK2 40           // ceil(N2/512)
#define G1 256            // chunk blocks, layer 1
#define G2 64             // chunk blocks, layer 2
#define CHUNK1 6250       // E1 / G1
#define CHUNK2 5000       // E2 / G2

typedef __bf16 bf16x8 __attribute__((ext_vector_type(8)));
typedef float f32x4 __attribute__((ext_vector_type(4)));
typedef uint16_t u16x4 __attribute__((ext_vector_type(4)));

__device__ inline uint16_t f2bf(float f) {
  uint32_t u = __float_as_uint(f);
  return (uint16_t)((u + 0x7fffu + ((u >> 16) & 1u)) >> 16);
}

// ---------------- dtype converts ----------------
__global__ __launch_bounds__(256) void cvt_f32_bf16_v4(
    const float* __restrict__ in, uint16_t* __restrict__ out, int n4) {
  int i = blockIdx.x * 256 + threadIdx.x;
  if (i >= n4) return;
  float4 v = reinterpret_cast<const float4*>(in)[i];
  u16x4 o = {f2bf(v.x), f2bf(v.y), f2bf(v.z), f2bf(v.w)};
  reinterpret_cast<u16x4*>(out)[i] = o;
}

__global__ __launch_bounds__(256) void cvt_wcat(
    const float* __restrict__ Wl, const float* __restrict__ Wr,
    uint16_t* __restrict__ out) {
  int i = blockIdx.x * 256 + threadIdx.x;  // 65536 total
  int j = i >> 8, k = i & 255;
  float v = (k < 128) ? Wl[j * 128 + k] : Wr[j * 128 + (k - 128)];
  out[i] = f2bf(v);
}

__global__ __launch_bounds__(256) void cvt_small(
    const float* __restrict__ in, uint16_t* __restrict__ out, int n) {
  int i = blockIdx.x * 256 + threadIdx.x;
  if (i < n) out[i] = f2bf(in[i]);
}

// ---------------- scan-based multi-split (no global atomics) ----------------
// pass 1: per-chunk LDS histogram over buckets; H[g*nb + b] dense write.
__global__ __launch_bounds__(256) void msplit_count(
    const int* __restrict__ dst, int* __restrict__ H, int E, int nb, int chunk) {
  __shared__ int hist[256];
  int g = blockIdx.x, t = threadIdx.x;
  hist[t] = 0;
  __syncthreads();
  int e0 = g * chunk, e1 = min(e0 + chunk, E);
  for (int e = e0 + t; e < e1; e += 256) atomicAdd(&hist[dst[e] >> 9], 1);
  __syncthreads();
  if (t < nb) H[g * nb + t] = hist[t];
}

// pass 2: per-bucket exclusive scan over the G chunk-blocks; totals -> T.
__global__ __launch_bounds__(256) void msplit_scan(
    int* __restrict__ H, int* __restrict__ T, int nb, int G) {
  __shared__ int sm[256];
  int b = blockIdx.x, t = threadIdx.x;
  int v = (t < G) ? H[t * nb + b] : 0;
  sm[t] = v;
  __syncthreads();
#pragma unroll
  for (int off = 1; off < 256; off <<= 1) {
    int u = (t >= off) ? sm[t - off] : 0;
    __syncthreads();
    sm[t] += u;
    __syncthreads();
  }
  if (t < G) H[t * nb + b] = sm[t] - v;  // exclusive
  if (t == 0) T[b] = sm[G - 1];          // inclusive total
}

// pass 3: exclusive scan of bucket totals -> bucket bases Bb. nb <= 256.
__global__ __launch_bounds__(256) void msplit_base(
    const int* __restrict__ T, int* __restrict__ Bb, int nb) {
  __shared__ int sm[256];
  int t = threadIdx.x;
  int v = (t < nb) ? T[t] : 0;
  sm[t] = v;
  __syncthreads();
#pragma unroll
  for (int off = 1; off < 256; off <<= 1) {
    int u = (t >= off) ? sm[t - off] : 0;
    __syncthreads();
    sm[t] += u;
    __syncthreads();
  }
  if (t < nb) Bb[t] = sm[t] - v;
}

// pass 4: place packed (src | dstLow<<18) at precomputed LDS-cursor offsets.
__global__ __launch_bounds__(256) void msplit_place(
    const int* __restrict__ src, const int* __restrict__ dst,
    const int* __restrict__ H, const int* __restrict__ Bb,
    uint32_t* __restrict__ pairs, int E, int nb, int chunk) {
  __shared__ int curs[256];
  int g = blockIdx.x, t = threadIdx.x;
  if (t < nb) curs[t] = Bb[t] + H[g * nb + t];
  __syncthreads();
  int e0 = g * chunk, e1 = min(e0 + chunk, E);
  for (int e = e0 + t; e < e1; e += 256) {
    int d = dst[e];
    int b = d >> 9;
    int p = atomicAdd(&curs[b], 1);
    pairs[p] = (uint32_t)src[e] | ((uint32_t)(d & 511) << 18);
  }
}

// per-bucket degree count via LDS counters (512 dsts / bucket)
__global__ __launch_bounds__(256) void bdeg512(
    const uint32_t* __restrict__ pairs, const int* __restrict__ Bb,
    const int* __restrict__ T, int* __restrict__ deg, int ndst) {
  __shared__ int cnt[512];
  int b = blockIdx.x, t = threadIdx.x;
  cnt[t] = 0;
  cnt[t + 256] = 0;
  __syncthreads();
  int s0 = Bb[b], n = T[b];
  for (int i = t; i < n; i += 256) atomicAdd(&cnt[pairs[s0 + i] >> 18], 1);
  __syncthreads();
  int d0 = b << 9;
#pragma unroll
  for (int j = 0; j < 2; ++j) {
    int dd = d0 + t + j * 256;
    if (dd < ndst) deg[dd] = cnt[t + j * 256];
  }
}

// per-bucket place into CSR esrc via LDS cursors (dense ~32KB write window)
__global__ __launch_bounds__(256) void bplace512(
    const uint32_t* __restrict__ pairs, const int* __restrict__ Bb,
    const int* __restrict__ T, const int* __restrict__ R,
    int* __restrict__ esrc, int ndst) {
  __shared__ int curs[512];
  int b = blockIdx.x, t = threadIdx.x;
  int d0 = b << 9;
#pragma unroll
  for (int j = 0; j < 2; ++j) {
    int dd = d0 + t + j * 256;
    curs[t + j * 256] = (dd < ndst) ? R[dd] : 0;
  }
  __syncthreads();
  int s0 = Bb[b], n = T[b];
  for (int i = t; i < n; i += 256) {
    uint32_t pk = pairs[s0 + i];
    int p = atomicAdd(&curs[pk >> 18], 1);
    esrc[p] = (int)(pk & 0x3FFFFu);
  }
}

// ---------------- scan (R from deg) ----------------
__global__ __launch_bounds__(256) void sage_scan_local(
    const int* __restrict__ deg, int* __restrict__ R, int* __restrict__ part, int N) {
  __shared__ int sm[256];
  int t = threadIdx.x;
  int base = blockIdx.x * 512;
  int i0 = base + 2 * t, i1 = base + 2 * t + 1;
  int a = (i0 < N) ? deg[i0] : 0;
  int b = (i1 < N) ? deg[i1] : 0;
  int s = a + b;
  sm[t] = s;
  __syncthreads();
#pragma unroll
  for (int off = 1; off < 256; off <<= 1) {
    int v = (t >= off) ? sm[t - off] : 0;
    __syncthreads();
    sm[t] += v;
    __syncthreads();
  }
  int excl = sm[t] - s;
  if (i0 < N) R[i0] = excl;
  if (i1 < N) R[i1] = excl + a;
  if (t == 255) part[blockIdx.x] = sm[255];
}

__global__ __launch_bounds__(256) void sage_scan_part(int* __restrict__ part, int B) {
  __shared__ int sm[256];
  int t = threadIdx.x;
  int v = (t < B) ? part[t] : 0;
  sm[t] = v;
  __syncthreads();
#pragma unroll
  for (int off = 1; off < 256; off <<= 1) {
    int u = (t >= off) ? sm[t - off] : 0;
    __syncthreads();
    sm[t] += u;
    __syncthreads();
  }
  if (t < B) part[t] = sm[t] - v;
}

__global__ __launch_bounds__(256) void sage_addback(
    int* __restrict__ R, const int* __restrict__ part, int N) {
  int i = blockIdx.x * 256 + threadIdx.x;
  if (i < N) R[i] += part[i >> 9];
}

// ---------------- gather-mean (bf16 in), layer 1: 64 lanes/dst ----------------
__global__ __launch_bounds__(256) void sage_gather1(
    const uint16_t* __restrict__ xbf, const int* __restrict__ esrc,
    const int* __restrict__ R, const int* __restrict__ deg,
    uint16_t* __restrict__ agg) {
  int d = blockIdx.x * 4 + (threadIdx.x >> 6);
  int c = threadIdx.x & 63;
  if (d >= CN1) return;
  int start = R[d], n = deg[d];
  const uint32_t* xw = reinterpret_cast<const uint32_t*>(xbf);
  float a0 = 0.f, a1 = 0.f;
  int i = 0;
  for (; i + 4 <= n; i += 4) {
    int s0 = esrc[start + i + 0];
    int s1 = esrc[start + i + 1];
    int s2 = esrc[start + i + 2];
    int s3 = esrc[start + i + 3];
    uint32_t v0 = xw[(size_t)s0 * 64 + c];
    uint32_t v1 = xw[(size_t)s1 * 64 + c];
    uint32_t v2 = xw[(size_t)s2 * 64 + c];
    uint32_t v3 = xw[(size_t)s3 * 64 + c];
    a0 += __uint_as_float(v0 << 16) + __uint_as_float(v1 << 16) +
          __uint_as_float(v2 << 16) + __uint_as_float(v3 << 16);
    a1 += __uint_as_float(v0 & 0xffff0000u) + __uint_as_float(v1 & 0xffff0000u) +
          __uint_as_float(v2 & 0xffff0000u) + __uint_as_float(v3 & 0xffff0000u);
  }
  for (; i < n; ++i) {
    uint32_t v = xw[(size_t)esrc[start + i] * 64 + c];
    a0 += __uint_as_float(v << 16);
    a1 += __uint_as_float(v & 0xffff0000u);
  }
  float inv = 1.0f / fmaxf((float)n, 1.0f);
  a0 *= inv; a1 *= inv;
  uint32_t packed = (uint32_t)f2bf(a0) | ((uint32_t)f2bf(a1) << 16);
  reinterpret_cast<uint32_t*>(agg)[(size_t)d * 64 + c] = packed;
}

// ---------------- gather-mean (bf16 in), layer 2: 32 lanes/dst, f32 out ----
__global__ __launch_bounds__(256) void sage_gather2(
    const uint16_t* __restrict__ t2, const int* __restrict__ esrc,
    const int* __restrict__ R, const int* __restrict__ deg,
    float* __restrict__ agg) {
  int d = blockIdx.x * 8 + (threadIdx.x >> 5);
  int c = threadIdx.x & 31;
  if (d >= CN2) return;
  int start = R[d], n = deg[d];
  const uint32_t* tw = reinterpret_cast<const uint32_t*>(t2);
  float a0 = 0.f, a1 = 0.f;
  int i = 0;
  for (; i + 4 <= n; i += 4) {
    int s0 = esrc[start + i + 0];
    int s1 = esrc[start + i + 1];
    int s2 = esrc[start + i + 2];
    int s3 = esrc[start + i + 3];
    uint32_t v0 = tw[(size_t)s0 * 32 + c];
    uint32_t v1 = tw[(size_t)s1 * 32 + c];
    uint32_t v2 = tw[(size_t)s2 * 32 + c];
    uint32_t v3 = tw[(size_t)s3 * 32 + c];
    a0 += __uint_as_float(v0 << 16) + __uint_as_float(v1 << 16) +
          __uint_as_float(v2 << 16) + __uint_as_float(v3 << 16);
    a1 += __uint_as_float(v0 & 0xffff0000u) + __uint_as_float(v1 & 0xffff0000u) +
          __uint_as_float(v2 & 0xffff0000u) + __uint_as_float(v3 & 0xffff0000u);
  }
  for (; i < n; ++i) {
    uint32_t v = tw[(size_t)esrc[start + i] * 32 + c];
    a0 += __uint_as_float(v << 16);
    a1 += __uint_as_float(v & 0xffff0000u);
  }
  float inv = 1.0f / fmaxf((float)n, 1.0f);
  float2 o = {a0 * inv, a1 * inv};
  reinterpret_cast<float2*>(agg)[(size_t)d * 32 + c] = o;
}

// ---------------- MEGA kernel ----------------
__global__ __launch_bounds__(256) void sage_mega(
    const uint16_t* __restrict__ agg, const uint16_t* __restrict__ xbf,
    const uint16_t* __restrict__ wcat, const uint16_t* __restrict__ w2cat,
    const float* __restrict__ bias, uint16_t* __restrict__ t2,
    float* __restrict__ outp) {
  __shared__ uint16_t lds[39936];
  uint16_t* As  = lds;            // [64][72]
  uint16_t* Ws  = lds + 4608;     // [256][72]  (phase 2: W2s [128][72])
  uint16_t* h1s = lds + 23040;    // [64][264]; epilogue: t2s[64][64]u16 + outs[64][64]f32

  const int tid = threadIdx.x;
  const int w = tid >> 6;
  const int lane = tid & 63;
  const int lr = lane >> 4;
  const int lc = lane & 15;
  const int row0 = blockIdx.x * 64;

  // ---- phase 1 ----
  f32x4 acc1[16];
#pragma unroll
  for (int n = 0; n < 16; ++n) acc1[n] = (f32x4)0.0f;

  for (int t = 0; t < 4; ++t) {
    const int k0 = t * 64;
    const uint16_t* Asrc = (t < 2) ? agg : xbf;
    const int koff = (t < 2) ? k0 : k0 - 128;

    int4 av[2];
#pragma unroll
    for (int i = 0; i < 2; ++i) {
      int q = tid + 256 * i;
      int r = q >> 3, c = q & 7;
      int rg = row0 + r;
      rg = rg < CN1 ? rg : CN1 - 1;
      av[i] = *reinterpret_cast<const int4*>(Asrc + (size_t)rg * CD_IN + koff + c * 8);
    }
    int4 wv[8];
#pragma unroll
    for (int i = 0; i < 8; ++i) {
      int q = tid + 256 * i;
      int r = q >> 3, c = q & 7;
      wv[i] = *reinterpret_cast<const int4*>(wcat + (size_t)r * 256 + k0 + c * 8);
    }
    __syncthreads();
#pragma unroll
    for (int i = 0; i < 2; ++i) {
      int q = tid + 256 * i;
      int r = q >> 3, c = q & 7;
      *reinterpret_cast<int4*>(&As[r * 72 + c * 8]) = av[i];
    }
#pragma unroll
    for (int i = 0; i < 8; ++i) {
      int q = tid + 256 * i;
      int r = q >> 3, c = q & 7;
      *reinterpret_cast<int4*>(&Ws[r * 72 + c * 8]) = wv[i];
    }
    __syncthreads();

#pragma unroll
    for (int ks = 0; ks < 2; ++ks) {
      const int kb = ks * 32 + lr * 8;
      bf16x8 af = *reinterpret_cast<const bf16x8*>(&As[(w * 16 + lc) * 72 + kb]);
#pragma unroll
      for (int n = 0; n < 16; ++n) {
        bf16x8 bfv = *reinterpret_cast<const bf16x8*>(&Ws[(n * 16 + lc) * 72 + kb]);
        acc1[n] = __builtin_amdgcn_mfma_f32_16x16x32_bf16(af, bfv, acc1[n], 0, 0, 0);
      }
    }
    __syncthreads();
  }

  // epilogue 1: bias + relu -> bf16 -> h1s
#pragma unroll
  for (int n = 0; n < 16; ++n) {
    float bb = bias[n * 16 + lc];
#pragma unroll
    for (int i = 0; i < 4; ++i) {
      float v = fmaxf(acc1[n][i] + bb, 0.0f);
      h1s[(w * 16 + lr * 4 + i) * 264 + n * 16 + lc] = f2bf(v);
    }
  }

  // ---- phase 2 ----
  f32x4 acc2[8];
#pragma unroll
  for (int n = 0; n < 8; ++n) acc2[n] = (f32x4)0.0f;

  for (int t = 0; t < 4; ++t) {
    const int k0 = t * 64;
    int4 wv[4];
#pragma unroll
    for (int i = 0; i < 4; ++i) {
      int q = tid + 256 * i;
      int r = q >> 3, c = q & 7;
      wv[i] = *reinterpret_cast<const int4*>(w2cat + (size_t)r * 256 + k0 + c * 8);
    }
    __syncthreads();
#pragma unroll
    for (int i = 0; i < 4; ++i) {
      int q = tid + 256 * i;
      int r = q >> 3, c = q & 7;
      *reinterpret_cast<int4*>(&Ws[r * 72 + c * 8]) = wv[i];
    }
    __syncthreads();

#pragma unroll
    for (int ks = 0; ks < 2; ++ks) {
      const int kb = ks * 32 + lr * 8;
      bf16x8 af = *reinterpret_cast<const bf16x8*>(&h1s[(w * 16 + lc) * 264 + k0 + kb]);
#pragma unroll
      for (int n = 0; n < 8; ++n) {
        bf16x8 bfv = *reinterpret_cast<const bf16x8*>(&Ws[(n * 16 + lc) * 72 + kb]);
        acc2[n] = __builtin_amdgcn_mfma_f32_16x16x32_bf16(af, bfv, acc2[n], 0, 0, 0);
      }
    }
  }

  // ---- epilogue 2: LDS-stage output tiles, then coalesced stores ----
  __syncthreads();
  uint16_t* t2s = h1s;                    // [64][64] u16 (8 KB)
  float* outs = (float*)(h1s + 4096);     // [64][64] f32 (16 KB)
#pragma unroll
  for (int i = 0; i < 4; ++i) {
    int rl = w * 16 + lr * 4 + i;
#pragma unroll
    for (int n = 0; n < 4; ++n) t2s[rl * 64 + n * 16 + lc] = f2bf(acc2[n][i]);
#pragma unroll
    for (int n = 0; n < 4; ++n) outs[rl * 64 + n * 16 + lc] = acc2[n + 4][i];
  }
  __syncthreads();
#pragma unroll
  for (int i = 0; i < 2; ++i) {
    int q = tid + 256 * i;
    int r = q >> 3, c = q & 7;
    int rg = row0 + r;
    if (rg < CN1)
      reinterpret_cast<int4*>(t2 + (size_t)rg * 64)[c] =
          *reinterpret_cast<const int4*>(&t2s[r * 64 + c * 8]);
  }
  if (row0 < CN2) {
#pragma unroll
    for (int i = 0; i < 4; ++i) {
      int q = tid + 256 * i;
      int r = q >> 4, c = q & 15;
      int rg = row0 + r;
      if (rg < CN2)
        reinterpret_cast<int4*>(outp + (size_t)rg * 64)[c] =
            *reinterpret_cast<const int4*>(&outs[r * 64 + c * 4]);
    }
  }
}

// ---------------- finalize: out = log_softmax(out + agg2 + b2) ----------------
__global__ __launch_bounds__(256) void sage_finalize(
    const float* __restrict__ agg2, const float* __restrict__ b,
    float* __restrict__ out) {
  int row = blockIdx.x * 4 + (threadIdx.x >> 6);
  int lane = threadIdx.x & 63;
  if (row >= CN2) return;
  size_t o = (size_t)row * CD_OUT + lane;
  float v = out[o] + agg2[o] + b[lane];
  float m = v;
#pragma unroll
  for (int d = 32; d > 0; d >>= 1) m = fmaxf(m, __shfl_xor(m, d));
  float e = expf(v - m);
  float s = e;
#pragma unroll
  for (int d = 32; d > 0; d >>= 1) s += __shfl_xor(s, d);
  out[o] = v - m - logf(s);
}

extern "C" void kernel_launch(void* const* d_in, const int* in_sizes, int n_in,
                              void* d_out, int out_size, void* d_ws, size_t ws_size,
                              hipStream_t stream) {
  const float* x    = (const float*)d_in[0];
  const int* src1   = (const int*)d_in[1];
  const int* dst1   = (const int*)d_in[2];
  const int* src2   = (const int*)d_in[3];
  const int* dst2   = (const int*)d_in[4];
  const float* W_l1 = (const float*)d_in[5];
  const float* b_l1 = (const float*)d_in[6];
  const float* W_r1 = (const float*)d_in[7];
  const float* W_l2 = (const float*)d_in[8];
  const float* b_l2 = (const float*)d_in[9];
  const float* W_r2 = (const float*)d_in[10];
  float* out = (float*)d_out;
  char* base = (char*)d_ws;

  // ---- workspace layout (bytes), ~111.5 MB ----
  uint16_t* x_bf  = (uint16_t*)base;                       // 51.2 MB
  uint16_t* t2_bf = (uint16_t*)(base + 51200000);          // 12.8 MB
  uint32_t* pairs1= (uint32_t*)(base + 64000000);          // 6.4 MB (E1*4)
  uint32_t* pairs2= (uint32_t*)(base + 70400000);          // 1.28 MB (E2*4)
  uint16_t* agg_bf= (uint16_t*)(base + 71680000);          // 25.6 MB
  float* agg2     = (float*)(base + 97280000);             // 5.12 MB
  int* deg1 = (int*)(base + 102400000);                    // 400 KB
  int* R1   = (int*)(base + 102800000);                    // 400 KB
  int* esrc1= (int*)(base + 103200000);                    // 6.4 MB
  int* deg2 = (int*)(base + 109600000);                    // 80 KB
  int* R2   = (int*)(base + 109680000);                    // 80 KB
  int* esrc2= (int*)(base + 109760000);                    // 1.28 MB
  int* H1   = (int*)(base + 111040000);                    // 200,704 B (G1*NBK1*4)
  int* H2   = (int*)(base + 111240704);                    // 10,240 B  (G2*NBK2*4)
  char* misc = base + 111250944;
  int* T1  = (int*)(misc);                                 // 784 B
  int* Bb1 = (int*)(misc + 1024);
  int* T2  = (int*)(misc + 2048);
  int* Bb2 = (int*)(misc + 3072);
  int* part1 = (int*)(misc + 4096);
  int* part2 = (int*)(misc + 5120);
  uint16_t* wcat  = (uint16_t*)(misc + 6144);              // 128 KB
  uint16_t* w2cat = wcat + 65536;                          // 64 KB

  if (ws_size < 112000000u) return;

  const int B1 = (CN1 + 511) / 512;  // 196
  const int B2 = (CN2 + 511) / 512;  // 40

  // ---- converts ----
  cvt_f32_bf16_v4<<<(CN0 * CD_IN / 4 + 255) / 256, 256, 0, stream>>>(x, x_bf, CN0 * CD_IN / 4);
  cvt_wcat<<<256, 256, 0, stream>>>(W_l1, W_r1, wcat);
  cvt_small<<<64, 256, 0, stream>>>(W_l2, w2cat, CD_OUT * CD_H);
  cvt_small<<<64, 256, 0, stream>>>(W_r2, w2cat + 16384, CD_OUT * CD_H);

  // ---- layer 1: multi-split -> CSR -> gather ----
  msplit_count<<<G1, 256, 0, stream>>>(dst1, H1, CE1, NBK1, CHUNK1);
  msplit_scan<<<NBK1, 256, 0, stream>>>(H1, T1, NBK1, G1);
  msplit_base<<<1, 256, 0, stream>>>(T1, Bb1, NBK1);
  msplit_place<<<G1, 256, 0, stream>>>(src1, dst1, H1, Bb1, pairs1, CE1, NBK1, CHUNK1);
  bdeg512<<<NBK1, 256, 0, stream>>>(pairs1, Bb1, T1, deg1, CN1);
  sage_scan_local<<<B1, 256, 0, stream>>>(deg1, R1, part1, CN1);
  sage_scan_part<<<1, 256, 0, stream>>>(part1, B1);
  sage_addback<<<(CN1 + 255) / 256, 256, 0, stream>>>(R1, part1, CN1);
  bplace512<<<NBK1, 256, 0, stream>>>(pairs1, Bb1, T1, R1, esrc1, CN1);
  sage_gather1<<<(CN1 + 3) / 4, 256, 0, stream>>>(x_bf, esrc1, R1, deg1, agg_bf);

  // ---- mega: h1 in LDS; writes t2 + out-partial ----
  sage_mega<<<(CN1 + 63) / 64, 256, 0, stream>>>(
      agg_bf, x_bf, wcat, w2cat, b_l1, t2_bf, out);

  // ---- layer 2: multi-split -> CSR -> gather ----
  msplit_count<<<G2, 256, 0, stream>>>(dst2, H2, CE2, NBK2, CHUNK2);
  msplit_scan<<<NBK2, 256, 0, stream>>>(H2, T2, NBK2, G2);
  msplit_base<<<1, 256, 0, stream>>>(T2, Bb2, NBK2);
  msplit_place<<<G2, 256, 0, stream>>>(src2, dst2, H2, Bb2, pairs2, CE2, NBK2, CHUNK2);
  bdeg512<<<NBK2, 256, 0, stream>>>(pairs2, Bb2, T2, deg2, CN2);
  sage_scan_local<<<B2, 256, 0, stream>>>(deg2, R2, part2, CN2);
  sage_scan_part<<<1, 256, 0, stream>>>(part2, B2);
  sage_addback<<<(CN2 + 255) / 256, 256, 0, stream>>>(R2, part2, CN2);
  bplace512<<<NBK2, 256, 0, stream>>>(pairs2, Bb2, T2, R2, esrc2, CN2);
  sage_gather2<<<(CN2 + 7) / 8, 256, 0, stream>>>(t2_bf, esrc2, R2, deg2, agg2);

  // ---- finalize ----
  sage_finalize<<<(CN2 + 3) / 4, 256, 0, stream>>>(agg2, b_l2, out);
}

// Round 8
// 347.345 us; speedup vs baseline: 2.5165x; 1.0540x over previous
//
#include <hip/hip_runtime.h>
#include <stdint.h>

// SAGE_876173328847: 2-layer bipartite SAGEConv (mean agg) + log_softmax.
// N0=200000, N1=100000, N2=20000, E1=1.6M, E2=320K, D_IN=128, D_H=256, D_OUT=64.
//
// R1: atomic scatter -> CSR build + gather (3309 -> 667 us).
// R2/R3: bf16 heavy path + MFMA GEMMs (667 -> 547 us).
// R4: fused mega-kernel, h1 lives only in LDS (547 -> 472 us).
// R6->R7: scan-based multi-split CSR build, zero global atomics (874 -> 366 us).
// R8: mega had WRITE 210 MB vs 18 MB logical and the coalesced epilogue (R5)
//     didn't move it -> scratch SPILL traffic (live regs ~115 > alloc 100).
//     Fix: split phase 1 into two col-halves (acc 64->32 VGPR, Ws tile halved),
//     peak live ~75 VGPR, LDS 79.9->60 KB, still 2 blocks/CU.

#define CN0 200000
#define CN1 100000
#define CN2 20000
#define CE1 1600000
#define CE2 320000
#define CD_IN 128
#define CD_H 256
#define CD_OUT 64

// multi-split geometry: bucket = dst >> 9 (512 dsts per bucket)
#define NBK1 196          // ceil(N1/512)
#define NBK2 40           // ceil(N2/512)
#define G1 256            // chunk blocks, layer 1
#define G2 64             // chunk blocks, layer 2
#define CHUNK1 6250       // E1 / G1
#define CHUNK2 5000       // E2 / G2

typedef __bf16 bf16x8 __attribute__((ext_vector_type(8)));
typedef float f32x4 __attribute__((ext_vector_type(4)));
typedef uint16_t u16x4 __attribute__((ext_vector_type(4)));

__device__ inline uint16_t f2bf(float f) {
  uint32_t u = __float_as_uint(f);
  return (uint16_t)((u + 0x7fffu + ((u >> 16) & 1u)) >> 16);
}

// ---------------- dtype converts ----------------
__global__ __launch_bounds__(256) void cvt_f32_bf16_v4(
    const float* __restrict__ in, uint16_t* __restrict__ out, int n4) {
  int i = blockIdx.x * 256 + threadIdx.x;
  if (i >= n4) return;
  float4 v = reinterpret_cast<const float4*>(in)[i];
  u16x4 o = {f2bf(v.x), f2bf(v.y), f2bf(v.z), f2bf(v.w)};
  reinterpret_cast<u16x4*>(out)[i] = o;
}

__global__ __launch_bounds__(256) void cvt_wcat(
    const float* __restrict__ Wl, const float* __restrict__ Wr,
    uint16_t* __restrict__ out) {
  int i = blockIdx.x * 256 + threadIdx.x;  // 65536 total
  int j = i >> 8, k = i & 255;
  float v = (k < 128) ? Wl[j * 128 + k] : Wr[j * 128 + (k - 128)];
  out[i] = f2bf(v);
}

__global__ __launch_bounds__(256) void cvt_small(
    const float* __restrict__ in, uint16_t* __restrict__ out, int n) {
  int i = blockIdx.x * 256 + threadIdx.x;
  if (i < n) out[i] = f2bf(in[i]);
}

// ---------------- scan-based multi-split (no global atomics) ----------------
__global__ __launch_bounds__(256) void msplit_count(
    const int* __restrict__ dst, int* __restrict__ H, int E, int nb, int chunk) {
  __shared__ int hist[256];
  int g = blockIdx.x, t = threadIdx.x;
  hist[t] = 0;
  __syncthreads();
  int e0 = g * chunk, e1 = min(e0 + chunk, E);
  for (int e = e0 + t; e < e1; e += 256) atomicAdd(&hist[dst[e] >> 9], 1);
  __syncthreads();
  if (t < nb) H[g * nb + t] = hist[t];
}

__global__ __launch_bounds__(256) void msplit_scan(
    int* __restrict__ H, int* __restrict__ T, int nb, int G) {
  __shared__ int sm[256];
  int b = blockIdx.x, t = threadIdx.x;
  int v = (t < G) ? H[t * nb + b] : 0;
  sm[t] = v;
  __syncthreads();
#pragma unroll
  for (int off = 1; off < 256; off <<= 1) {
    int u = (t >= off) ? sm[t - off] : 0;
    __syncthreads();
    sm[t] += u;
    __syncthreads();
  }
  if (t < G) H[t * nb + b] = sm[t] - v;  // exclusive
  if (t == 0) T[b] = sm[G - 1];          // inclusive total
}

__global__ __launch_bounds__(256) void msplit_base(
    const int* __restrict__ T, int* __restrict__ Bb, int nb) {
  __shared__ int sm[256];
  int t = threadIdx.x;
  int v = (t < nb) ? T[t] : 0;
  sm[t] = v;
  __syncthreads();
#pragma unroll
  for (int off = 1; off < 256; off <<= 1) {
    int u = (t >= off) ? sm[t - off] : 0;
    __syncthreads();
    sm[t] += u;
    __syncthreads();
  }
  if (t < nb) Bb[t] = sm[t] - v;
}

__global__ __launch_bounds__(256) void msplit_place(
    const int* __restrict__ src, const int* __restrict__ dst,
    const int* __restrict__ H, const int* __restrict__ Bb,
    uint32_t* __restrict__ pairs, int E, int nb, int chunk) {
  __shared__ int curs[256];
  int g = blockIdx.x, t = threadIdx.x;
  if (t < nb) curs[t] = Bb[t] + H[g * nb + t];
  __syncthreads();
  int e0 = g * chunk, e1 = min(e0 + chunk, E);
  for (int e = e0 + t; e < e1; e += 256) {
    int d = dst[e];
    int b = d >> 9;
    int p = atomicAdd(&curs[b], 1);
    pairs[p] = (uint32_t)src[e] | ((uint32_t)(d & 511) << 18);
  }
}

__global__ __launch_bounds__(256) void bdeg512(
    const uint32_t* __restrict__ pairs, const int* __restrict__ Bb,
    const int* __restrict__ T, int* __restrict__ deg, int ndst) {
  __shared__ int cnt[512];
  int b = blockIdx.x, t = threadIdx.x;
  cnt[t] = 0;
  cnt[t + 256] = 0;
  __syncthreads();
  int s0 = Bb[b], n = T[b];
  for (int i = t; i < n; i += 256) atomicAdd(&cnt[pairs[s0 + i] >> 18], 1);
  __syncthreads();
  int d0 = b << 9;
#pragma unroll
  for (int j = 0; j < 2; ++j) {
    int dd = d0 + t + j * 256;
    if (dd < ndst) deg[dd] = cnt[t + j * 256];
  }
}

__global__ __launch_bounds__(256) void bplace512(
    const uint32_t* __restrict__ pairs, const int* __restrict__ Bb,
    const int* __restrict__ T, const int* __restrict__ R,
    int* __restrict__ esrc, int ndst) {
  __shared__ int curs[512];
  int b = blockIdx.x, t = threadIdx.x;
  int d0 = b << 9;
#pragma unroll
  for (int j = 0; j < 2; ++j) {
    int dd = d0 + t + j * 256;
    curs[t + j * 256] = (dd < ndst) ? R[dd] : 0;
  }
  __syncthreads();
  int s0 = Bb[b], n = T[b];
  for (int i = t; i < n; i += 256) {
    uint32_t pk = pairs[s0 + i];
    int p = atomicAdd(&curs[pk >> 18], 1);
    esrc[p] = (int)(pk & 0x3FFFFu);
  }
}

// ---------------- scan (R from deg) ----------------
__global__ __launch_bounds__(256) void sage_scan_local(
    const int* __restrict__ deg, int* __restrict__ R, int* __restrict__ part, int N) {
  __shared__ int sm[256];
  int t = threadIdx.x;
  int base = blockIdx.x * 512;
  int i0 = base + 2 * t, i1 = base + 2 * t + 1;
  int a = (i0 < N) ? deg[i0] : 0;
  int b = (i1 < N) ? deg[i1] : 0;
  int s = a + b;
  sm[t] = s;
  __syncthreads();
#pragma unroll
  for (int off = 1; off < 256; off <<= 1) {
    int v = (t >= off) ? sm[t - off] : 0;
    __syncthreads();
    sm[t] += v;
    __syncthreads();
  }
  int excl = sm[t] - s;
  if (i0 < N) R[i0] = excl;
  if (i1 < N) R[i1] = excl + a;
  if (t == 255) part[blockIdx.x] = sm[255];
}

__global__ __launch_bounds__(256) void sage_scan_part(int* __restrict__ part, int B) {
  __shared__ int sm[256];
  int t = threadIdx.x;
  int v = (t < B) ? part[t] : 0;
  sm[t] = v;
  __syncthreads();
#pragma unroll
  for (int off = 1; off < 256; off <<= 1) {
    int u = (t >= off) ? sm[t - off] : 0;
    __syncthreads();
    sm[t] += u;
    __syncthreads();
  }
  if (t < B) part[t] = sm[t] - v;
}

__global__ __launch_bounds__(256) void sage_addback(
    int* __restrict__ R, const int* __restrict__ part, int N) {
  int i = blockIdx.x * 256 + threadIdx.x;
  if (i < N) R[i] += part[i >> 9];
}

// ---------------- gather-mean (bf16 in), layer 1: 64 lanes/dst ----------------
__global__ __launch_bounds__(256) void sage_gather1(
    const uint16_t* __restrict__ xbf, const int* __restrict__ esrc,
    const int* __restrict__ R, const int* __restrict__ deg,
    uint16_t* __restrict__ agg) {
  int d = blockIdx.x * 4 + (threadIdx.x >> 6);
  int c = threadIdx.x & 63;
  if (d >= CN1) return;
  int start = R[d], n = deg[d];
  const uint32_t* xw = reinterpret_cast<const uint32_t*>(xbf);
  float a0 = 0.f, a1 = 0.f;
  int i = 0;
  for (; i + 4 <= n; i += 4) {
    int s0 = esrc[start + i + 0];
    int s1 = esrc[start + i + 1];
    int s2 = esrc[start + i + 2];
    int s3 = esrc[start + i + 3];
    uint32_t v0 = xw[(size_t)s0 * 64 + c];
    uint32_t v1 = xw[(size_t)s1 * 64 + c];
    uint32_t v2 = xw[(size_t)s2 * 64 + c];
    uint32_t v3 = xw[(size_t)s3 * 64 + c];
    a0 += __uint_as_float(v0 << 16) + __uint_as_float(v1 << 16) +
          __uint_as_float(v2 << 16) + __uint_as_float(v3 << 16);
    a1 += __uint_as_float(v0 & 0xffff0000u) + __uint_as_float(v1 & 0xffff0000u) +
          __uint_as_float(v2 & 0xffff0000u) + __uint_as_float(v3 & 0xffff0000u);
  }
  for (; i < n; ++i) {
    uint32_t v = xw[(size_t)esrc[start + i] * 64 + c];
    a0 += __uint_as_float(v << 16);
    a1 += __uint_as_float(v & 0xffff0000u);
  }
  float inv = 1.0f / fmaxf((float)n, 1.0f);
  a0 *= inv; a1 *= inv;
  uint32_t packed = (uint32_t)f2bf(a0) | ((uint32_t)f2bf(a1) << 16);
  reinterpret_cast<uint32_t*>(agg)[(size_t)d * 64 + c] = packed;
}

// ---------------- gather-mean (bf16 in), layer 2: 32 lanes/dst, f32 out ----
__global__ __launch_bounds__(256) void sage_gather2(
    const uint16_t* __restrict__ t2, const int* __restrict__ esrc,
    const int* __restrict__ R, const int* __restrict__ deg,
    float* __restrict__ agg) {
  int d = blockIdx.x * 8 + (threadIdx.x >> 5);
  int c = threadIdx.x & 31;
  if (d >= CN2) return;
  int start = R[d], n = deg[d];
  const uint32_t* tw = reinterpret_cast<const uint32_t*>(t2);
  float a0 = 0.f, a1 = 0.f;
  int i = 0;
  for (; i + 4 <= n; i += 4) {
    int s0 = esrc[start + i + 0];
    int s1 = esrc[start + i + 1];
    int s2 = esrc[start + i + 2];
    int s3 = esrc[start + i + 3];
    uint32_t v0 = tw[(size_t)s0 * 32 + c];
    uint32_t v1 = tw[(size_t)s1 * 32 + c];
    uint32_t v2 = tw[(size_t)s2 * 32 + c];
    uint32_t v3 = tw[(size_t)s3 * 32 + c];
    a0 += __uint_as_float(v0 << 16) + __uint_as_float(v1 << 16) +
          __uint_as_float(v2 << 16) + __uint_as_float(v3 << 16);
    a1 += __uint_as_float(v0 & 0xffff0000u) + __uint_as_float(v1 & 0xffff0000u) +
          __uint_as_float(v2 & 0xffff0000u) + __uint_as_float(v3 & 0xffff0000u);
  }
  for (; i < n; ++i) {
    uint32_t v = tw[(size_t)esrc[start + i] * 32 + c];
    a0 += __uint_as_float(v << 16);
    a1 += __uint_as_float(v & 0xffff0000u);
  }
  float inv = 1.0f / fmaxf((float)n, 1.0f);
  float2 o = {a0 * inv, a1 * inv};
  reinterpret_cast<float2*>(agg)[(size_t)d * 32 + c] = o;
}

// ---------------- MEGA kernel (R8: spill-free, 60 KB LDS) ----------------
// Per 64-row block (4 waves; wave w owns rows w*16..w*16+15):
//   phase 1 (2 col-halves h): acc[8] = [agg|x] @ Wcat[h*128..+128]^T
//     -> relu+bias -> h1s bf16.  (acc 32 VGPR, Ws tile [128][72])
//   phase 2: acc2 = h1 @ W2cat^T (cols 0..63 -> t2, 64..127 -> out partial)
//   epilogue: stage tiles in LDS (h1s dead), coalesced int4 stores.
__global__ __launch_bounds__(256, 2) void sage_mega(
    const uint16_t* __restrict__ agg, const uint16_t* __restrict__ xbf,
    const uint16_t* __restrict__ wcat, const uint16_t* __restrict__ w2cat,
    const float* __restrict__ bias, uint16_t* __restrict__ t2,
    float* __restrict__ outp) {
  __shared__ uint16_t lds[30720];  // 60 KB
  uint16_t* As  = lds;             // [64][72]   (4608)
  uint16_t* Ws  = lds + 4608;      // [128][72]  (9216)
  uint16_t* h1s = lds + 13824;     // [64][264]  (16896); epilogue: t2s+outs (24 KB)

  const int tid = threadIdx.x;
  const int w = tid >> 6;
  const int lane = tid & 63;
  const int lr = lane >> 4;
  const int lc = lane & 15;
  const int row0 = blockIdx.x * 64;

  // ---- phase 1: two column-halves ----
  for (int h = 0; h < 2; ++h) {
    f32x4 acc[8];
#pragma unroll
    for (int n = 0; n < 8; ++n) acc[n] = (f32x4)0.0f;

    for (int t = 0; t < 4; ++t) {
      const int k0 = t * 64;
      const uint16_t* Asrc = (t < 2) ? agg : xbf;
      const int koff = (t < 2) ? k0 : k0 - 128;

      // A tile: 64 rows x 64 k = 512 int4 -> 2/thread
      int4 av[2];
#pragma unroll
      for (int i = 0; i < 2; ++i) {
        int q = tid + 256 * i;
        int r = q >> 3, c = q & 7;
        int rg = row0 + r;
        rg = rg < CN1 ? rg : CN1 - 1;
        av[i] = *reinterpret_cast<const int4*>(Asrc + (size_t)rg * CD_IN + koff + c * 8);
      }
      // W half-tile: 128 rows x 64 k = 1024 int4 -> 4/thread
      int4 wv[4];
#pragma unroll
      for (int i = 0; i < 4; ++i) {
        int q = tid + 256 * i;
        int r = q >> 3, c = q & 7;
        wv[i] = *reinterpret_cast<const int4*>(wcat + (size_t)(h * 128 + r) * 256 + k0 + c * 8);
      }
      __syncthreads();   // prior MFMA reads of As/Ws complete
#pragma unroll
      for (int i = 0; i < 2; ++i) {
        int q = tid + 256 * i;
        int r = q >> 3, c = q & 7;
        *reinterpret_cast<int4*>(&As[r * 72 + c * 8]) = av[i];
      }
#pragma unroll
      for (int i = 0; i < 4; ++i) {
        int q = tid + 256 * i;
        int r = q >> 3, c = q & 7;
        *reinterpret_cast<int4*>(&Ws[r * 72 + c * 8]) = wv[i];
      }
      __syncthreads();

#pragma unroll
      for (int ks = 0; ks < 2; ++ks) {
        const int kb = ks * 32 + lr * 8;
        bf16x8 af = *reinterpret_cast<const bf16x8*>(&As[(w * 16 + lc) * 72 + kb]);
#pragma unroll
        for (int n = 0; n < 8; ++n) {
          bf16x8 bfv = *reinterpret_cast<const bf16x8*>(&Ws[(n * 16 + lc) * 72 + kb]);
          acc[n] = __builtin_amdgcn_mfma_f32_16x16x32_bf16(af, bfv, acc[n], 0, 0, 0);
        }
      }
    }

    // epilogue half: bias + relu -> bf16 -> h1s cols h*128..h*128+127
#pragma unroll
    for (int n = 0; n < 8; ++n) {
      float bb = bias[h * 128 + n * 16 + lc];
#pragma unroll
      for (int i = 0; i < 4; ++i) {
        float v = fmaxf(acc[n][i] + bb, 0.0f);
        h1s[(w * 16 + lr * 4 + i) * 264 + h * 128 + n * 16 + lc] = f2bf(v);
      }
    }
  }
  __syncthreads();  // h1s complete before phase-2 reads

  // ---- phase 2: [t2 | out_part] = h1 @ W2cat^T ----
  f32x4 acc2[8];
#pragma unroll
  for (int n = 0; n < 8; ++n) acc2[n] = (f32x4)0.0f;

  for (int t = 0; t < 4; ++t) {
    const int k0 = t * 64;
    int4 wv[4];
#pragma unroll
    for (int i = 0; i < 4; ++i) {
      int q = tid + 256 * i;
      int r = q >> 3, c = q & 7;
      wv[i] = *reinterpret_cast<const int4*>(w2cat + (size_t)r * 256 + k0 + c * 8);
    }
    __syncthreads();   // prior reads of Ws complete
#pragma unroll
    for (int i = 0; i < 4; ++i) {
      int q = tid + 256 * i;
      int r = q >> 3, c = q & 7;
      *reinterpret_cast<int4*>(&Ws[r * 72 + c * 8]) = wv[i];
    }
    __syncthreads();

#pragma unroll
    for (int ks = 0; ks < 2; ++ks) {
      const int kb = ks * 32 + lr * 8;
      bf16x8 af = *reinterpret_cast<const bf16x8*>(&h1s[(w * 16 + lc) * 264 + k0 + kb]);
#pragma unroll
      for (int n = 0; n < 8; ++n) {
        bf16x8 bfv = *reinterpret_cast<const bf16x8*>(&Ws[(n * 16 + lc) * 72 + kb]);
        acc2[n] = __builtin_amdgcn_mfma_f32_16x16x32_bf16(af, bfv, acc2[n], 0, 0, 0);
      }
    }
  }

  // ---- epilogue 2: LDS-stage output tiles, then coalesced stores ----
  __syncthreads();
  uint16_t* t2s = h1s;                    // [64][64] u16 (8 KB)
  float* outs = (float*)(h1s + 4096);     // [64][64] f32 (16 KB)
#pragma unroll
  for (int i = 0; i < 4; ++i) {
    int rl = w * 16 + lr * 4 + i;
#pragma unroll
    for (int n = 0; n < 4; ++n) t2s[rl * 64 + n * 16 + lc] = f2bf(acc2[n][i]);
#pragma unroll
    for (int n = 0; n < 4; ++n) outs[rl * 64 + n * 16 + lc] = acc2[n + 4][i];
  }
  __syncthreads();
#pragma unroll
  for (int i = 0; i < 2; ++i) {
    int q = tid + 256 * i;
    int r = q >> 3, c = q & 7;
    int rg = row0 + r;
    if (rg < CN1)
      reinterpret_cast<int4*>(t2 + (size_t)rg * 64)[c] =
          *reinterpret_cast<const int4*>(&t2s[r * 64 + c * 8]);
  }
  if (row0 < CN2) {
#pragma unroll
    for (int i = 0; i < 4; ++i) {
      int q = tid + 256 * i;
      int r = q >> 4, c = q & 15;
      int rg = row0 + r;
      if (rg < CN2)
        reinterpret_cast<int4*>(outp + (size_t)rg * 64)[c] =
            *reinterpret_cast<const int4*>(&outs[r * 64 + c * 4]);
    }
  }
}

// ---------------- finalize: out = log_softmax(out + agg2 + b2) ----------------
__global__ __launch_bounds__(256) void sage_finalize(
    const float* __restrict__ agg2, const float* __restrict__ b,
    float* __restrict__ out) {
  int row = blockIdx.x * 4 + (threadIdx.x >> 6);
  int lane = threadIdx.x & 63;
  if (row >= CN2) return;
  size_t o = (size_t)row * CD_OUT + lane;
  float v = out[o] + agg2[o] + b[lane];
  float m = v;
#pragma unroll
  for (int d = 32; d > 0; d >>= 1) m = fmaxf(m, __shfl_xor(m, d));
  float e = expf(v - m);
  float s = e;
#pragma unroll
  for (int d = 32; d > 0; d >>= 1) s += __shfl_xor(s, d);
  out[o] = v - m - logf(s);
}

extern "C" void kernel_launch(void* const* d_in, const int* in_sizes, int n_in,
                              void* d_out, int out_size, void* d_ws, size_t ws_size,
                              hipStream_t stream) {
  const float* x    = (const float*)d_in[0];
  const int* src1   = (const int*)d_in[1];
  const int* dst1   = (const int*)d_in[2];
  const int* src2   = (const int*)d_in[3];
  const int* dst2   = (const int*)d_in[4];
  const float* W_l1 = (const float*)d_in[5];
  const float* b_l1 = (const float*)d_in[6];
  const float* W_r1 = (const float*)d_in[7];
  const float* W_l2 = (const float*)d_in[8];
  const float* b_l2 = (const float*)d_in[9];
  const float* W_r2 = (const float*)d_in[10];
  float* out = (float*)d_out;
  char* base = (char*)d_ws;

  // ---- workspace layout (bytes), ~111.5 MB ----
  uint16_t* x_bf  = (uint16_t*)base;                       // 51.2 MB
  uint16_t* t2_bf = (uint16_t*)(base + 51200000);          // 12.8 MB
  uint32_t* pairs1= (uint32_t*)(base + 64000000);          // 6.4 MB (E1*4)
  uint32_t* pairs2= (uint32_t*)(base + 70400000);          // 1.28 MB (E2*4)
  uint16_t* agg_bf= (uint16_t*)(base + 71680000);          // 25.6 MB
  float* agg2     = (float*)(base + 97280000);             // 5.12 MB
  int* deg1 = (int*)(base + 102400000);                    // 400 KB
  int* R1   = (int*)(base + 102800000);                    // 400 KB
  int* esrc1= (int*)(base + 103200000);                    // 6.4 MB
  int* deg2 = (int*)(base + 109600000);                    // 80 KB
  int* R2   = (int*)(base + 109680000);                    // 80 KB
  int* esrc2= (int*)(base + 109760000);                    // 1.28 MB
  int* H1   = (int*)(base + 111040000);                    // 200,704 B (G1*NBK1*4)
  int* H2   = (int*)(base + 111240704);                    // 10,240 B  (G2*NBK2*4)
  char* misc = base + 111250944;
  int* T1  = (int*)(misc);                                 // 784 B
  int* Bb1 = (int*)(misc + 1024);
  int* T2  = (int*)(misc + 2048);
  int* Bb2 = (int*)(misc + 3072);
  int* part1 = (int*)(misc + 4096);
  int* part2 = (int*)(misc + 5120);
  uint16_t* wcat  = (uint16_t*)(misc + 6144);              // 128 KB
  uint16_t* w2cat = wcat + 65536;                          // 64 KB

  if (ws_size < 112000000u) return;

  const int B1 = (CN1 + 511) / 512;  // 196
  const int B2 = (CN2 + 511) / 512;  // 40

  // ---- converts ----
  cvt_f32_bf16_v4<<<(CN0 * CD_IN / 4 + 255) / 256, 256, 0, stream>>>(x, x_bf, CN0 * CD_IN / 4);
  cvt_wcat<<<256, 256, 0, stream>>>(W_l1, W_r1, wcat);
  cvt_small<<<64, 256, 0, stream>>>(W_l2, w2cat, CD_OUT * CD_H);
  cvt_small<<<64, 256, 0, stream>>>(W_r2, w2cat + 16384, CD_OUT * CD_H);

  // ---- layer 1: multi-split -> CSR -> gather ----
  msplit_count<<<G1, 256, 0, stream>>>(dst1, H1, CE1, NBK1, CHUNK1);
  msplit_scan<<<NBK1, 256, 0, stream>>>(H1, T1, NBK1, G1);
  msplit_base<<<1, 256, 0, stream>>>(T1, Bb1, NBK1);
  msplit_place<<<G1, 256, 0, stream>>>(src1, dst1, H1, Bb1, pairs1, CE1, NBK1, CHUNK1);
  bdeg512<<<NBK1, 256, 0, stream>>>(pairs1, Bb1, T1, deg1, CN1);
  sage_scan_local<<<B1, 256, 0, stream>>>(deg1, R1, part1, CN1);
  sage_scan_part<<<1, 256, 0, stream>>>(part1, B1);
  sage_addback<<<(CN1 + 255) / 256, 256, 0, stream>>>(R1, part1, CN1);
  bplace512<<<NBK1, 256, 0, stream>>>(pairs1, Bb1, T1, R1, esrc1, CN1);
  sage_gather1<<<(CN1 + 3) / 4, 256, 0, stream>>>(x_bf, esrc1, R1, deg1, agg_bf);

  // ---- mega: h1 in LDS; writes t2 + out-partial ----
  sage_mega<<<(CN1 + 63) / 64, 256, 0, stream>>>(
      agg_bf, x_bf, wcat, w2cat, b_l1, t2_bf, out);

  // ---- layer 2: multi-split -> CSR -> gather ----
  msplit_count<<<G2, 256, 0, stream>>>(dst2, H2, CE2, NBK2, CHUNK2);
  msplit_scan<<<NBK2, 256, 0, stream>>>(H2, T2, NBK2, G2);
  msplit_base<<<1, 256, 0, stream>>>(T2, Bb2, NBK2);
  msplit_place<<<G2, 256, 0, stream>>>(src2, dst2, H2, Bb2, pairs2, CE2, NBK2, CHUNK2);
  bdeg512<<<NBK2, 256, 0, stream>>>(pairs2, Bb2, T2, deg2, CN2);
  sage_scan_local<<<B2, 256, 0, stream>>>(deg2, R2, part2, CN2);
  sage_scan_part<<<1, 256, 0, stream>>>(part2, B2);
  sage_addback<<<(CN2 + 255) / 256, 256, 0, stream>>>(R2, part2, CN2);
  bplace512<<<NBK2, 256, 0, stream>>>(pairs2, Bb2, T2, R2, esrc2, CN2);
  sage_gather2<<<(CN2 + 7) / 8, 256, 0, stream>>>(t2_bf, esrc2, R2, deg2, agg2);

  // ---- finalize ----
  sage_finalize<<<(CN2 + 3) / 4, 256, 0, stream>>>(agg2, b_l2, out);
}

// Round 9
// 285.519 us; speedup vs baseline: 3.0615x; 1.2165x over previous
//
#include <hip/hip_runtime.h>
#include <stdint.h>

// SAGE_876173328847: 2-layer bipartite SAGEConv (mean agg) + log_softmax.
// N0=200000, N1=100000, N2=20000, E1=1.6M, E2=320K, D_IN=128, D_H=256, D_OUT=64.
//
// R1: atomic scatter -> CSR build + gather (3309 -> 667 us).
// R2/R3: bf16 heavy path + MFMA GEMMs (667 -> 547 us).
// R4: fused mega-kernel, h1 lives only in LDS (547 -> 472 us).
// R7: scan-based multi-split CSR build, zero global atomics (-> 366 us).
// R8: spill-free mega (WRITE 210->38 MB, 366 -> 347 us).
// R9: mega is latency-bound (MfmaUtil 7%, HBM 8%, occ 17%): add 2-phase
//     register prefetch (next tile's global loads issue before current MFMA),
//     setprio around MFMA, bias preload. Plus launch fusion: 22 -> 14
//     dispatches (dual-layer CSR build in shared launches; addback folded
//     into bplace/gather via R[d]+part[d>>9]; one weight-convert kernel).

#define CN0 200000
#define CN1 100000
#define CN2 20000
#define CE1 1600000
#define CE2 320000
#define CD_IN 128
#define CD_H 256
#define CD_OUT 64

// multi-split geometry: bucket = dst >> 9 (512 dsts per bucket)
#define NBK1 196          // ceil(N1/512)  (== scan_local block count B1)
#define NBK2 40           // ceil(N2/512)  (== B2)
#define G1 256            // chunk blocks, layer 1
#define G2 64             // chunk blocks, layer 2
#define CHUNK1 6250       // E1 / G1
#define CHUNK2 5000       // E2 / G2

typedef __bf16 bf16x8 __attribute__((ext_vector_type(8)));
typedef float f32x4 __attribute__((ext_vector_type(4)));
typedef uint16_t u16x4 __attribute__((ext_vector_type(4)));

__device__ inline uint16_t f2bf(float f) {
  uint32_t u = __float_as_uint(f);
  return (uint16_t)((u + 0x7fffu + ((u >> 16) & 1u)) >> 16);
}

// ---------------- dtype converts ----------------
__global__ __launch_bounds__(256) void cvt_f32_bf16_v4(
    const float* __restrict__ in, uint16_t* __restrict__ out, int n4) {
  int i = blockIdx.x * 256 + threadIdx.x;
  if (i >= n4) return;
  float4 v = reinterpret_cast<const float4*>(in)[i];
  u16x4 o = {f2bf(v.x), f2bf(v.y), f2bf(v.z), f2bf(v.w)};
  reinterpret_cast<u16x4*>(out)[i] = o;
}

// all weight converts in one launch: wcat[256][256] then w2cat[128][256]
__global__ __launch_bounds__(256) void cvt_weights(
    const float* __restrict__ Wl1, const float* __restrict__ Wr1,
    const float* __restrict__ Wl2, const float* __restrict__ Wr2,
    uint16_t* __restrict__ wcat, uint16_t* __restrict__ w2cat) {
  int i = blockIdx.x * 256 + threadIdx.x;  // 98304 total
  if (i < 65536) {
    int j = i >> 8, k = i & 255;
    float v = (k < 128) ? Wl1[j * 128 + k] : Wr1[j * 128 + (k - 128)];
    wcat[i] = f2bf(v);
  } else {
    int ii = i - 65536;                    // 0..32767
    int r = ii >> 8, k = ii & 255;
    float v = (r < 64) ? Wl2[r * 256 + k] : Wr2[(r - 64) * 256 + k];
    w2cat[ii] = f2bf(v);
  }
}

// ---------------- dual-layer scan-based multi-split ----------------
__global__ __launch_bounds__(256) void csr_count(
    const int* __restrict__ dst1, const int* __restrict__ dst2,
    int* __restrict__ H1, int* __restrict__ H2) {
  __shared__ int hist[256];
  int g = blockIdx.x, t = threadIdx.x;
  const int* dst; int* H; int E, nb, chunk;
  if (g < G1) { dst = dst1; H = H1; E = CE1; nb = NBK1; chunk = CHUNK1; }
  else { g -= G1; dst = dst2; H = H2; E = CE2; nb = NBK2; chunk = CHUNK2; }
  hist[t] = 0;
  __syncthreads();
  int e0 = g * chunk, e1 = min(e0 + chunk, E);
  for (int e = e0 + t; e < e1; e += 256) atomicAdd(&hist[dst[e] >> 9], 1);
  __syncthreads();
  if (t < nb) H[g * nb + t] = hist[t];
}

__global__ __launch_bounds__(256) void csr_scan(
    int* __restrict__ H1, int* __restrict__ H2,
    int* __restrict__ T1, int* __restrict__ T2) {
  __shared__ int sm[256];
  int b = blockIdx.x, t = threadIdx.x;
  int* H; int* T; int nb, G;
  if (b < NBK1) { H = H1; T = T1; nb = NBK1; G = G1; }
  else { b -= NBK1; H = H2; T = T2; nb = NBK2; G = G2; }
  int v = (t < G) ? H[t * nb + b] : 0;
  sm[t] = v;
  __syncthreads();
#pragma unroll
  for (int off = 1; off < 256; off <<= 1) {
    int u = (t >= off) ? sm[t - off] : 0;
    __syncthreads();
    sm[t] += u;
    __syncthreads();
  }
  if (t < G) H[t * nb + b] = sm[t] - v;  // exclusive over chunks
  if (t == 255) T[b] = sm[255];          // bucket total
}

__global__ __launch_bounds__(256) void csr_base(
    const int* __restrict__ T1, const int* __restrict__ T2,
    int* __restrict__ Bb1, int* __restrict__ Bb2) {
  __shared__ int sm[256];
  int t = threadIdx.x;
  const int* T; int* Bb; int nb;
  if (blockIdx.x == 0) { T = T1; Bb = Bb1; nb = NBK1; }
  else { T = T2; Bb = Bb2; nb = NBK2; }
  int v = (t < nb) ? T[t] : 0;
  sm[t] = v;
  __syncthreads();
#pragma unroll
  for (int off = 1; off < 256; off <<= 1) {
    int u = (t >= off) ? sm[t - off] : 0;
    __syncthreads();
    sm[t] += u;
    __syncthreads();
  }
  if (t < nb) Bb[t] = sm[t] - v;
}

__global__ __launch_bounds__(256) void csr_place(
    const int* __restrict__ src1, const int* __restrict__ dst1,
    const int* __restrict__ src2, const int* __restrict__ dst2,
    const int* __restrict__ H1, const int* __restrict__ H2,
    const int* __restrict__ Bb1, const int* __restrict__ Bb2,
    uint32_t* __restrict__ pairs1, uint32_t* __restrict__ pairs2) {
  __shared__ int curs[256];
  int g = blockIdx.x, t = threadIdx.x;
  const int* src; const int* dst; const int* H; const int* Bb;
  uint32_t* pairs; int E, nb, chunk;
  if (g < G1) { src = src1; dst = dst1; H = H1; Bb = Bb1; pairs = pairs1;
                E = CE1; nb = NBK1; chunk = CHUNK1; }
  else { g -= G1; src = src2; dst = dst2; H = H2; Bb = Bb2; pairs = pairs2;
         E = CE2; nb = NBK2; chunk = CHUNK2; }
  if (t < nb) curs[t] = Bb[t] + H[g * nb + t];
  __syncthreads();
  int e0 = g * chunk, e1 = min(e0 + chunk, E);
  for (int e = e0 + t; e < e1; e += 256) {
    int d = dst[e];
    int b = d >> 9;
    int p = atomicAdd(&curs[b], 1);
    pairs[p] = (uint32_t)src[e] | ((uint32_t)(d & 511) << 18);
  }
}

__global__ __launch_bounds__(256) void csr_bdeg(
    const uint32_t* __restrict__ pairs1, const uint32_t* __restrict__ pairs2,
    const int* __restrict__ Bb1, const int* __restrict__ Bb2,
    const int* __restrict__ T1, const int* __restrict__ T2,
    int* __restrict__ deg1, int* __restrict__ deg2) {
  __shared__ int cnt[512];
  int b = blockIdx.x, t = threadIdx.x;
  const uint32_t* pairs; const int* Bb; const int* T; int* deg; int ndst;
  if (b < NBK1) { pairs = pairs1; Bb = Bb1; T = T1; deg = deg1; ndst = CN1; }
  else { b -= NBK1; pairs = pairs2; Bb = Bb2; T = T2; deg = deg2; ndst = CN2; }
  cnt[t] = 0;
  cnt[t + 256] = 0;
  __syncthreads();
  int s0 = Bb[b], n = T[b];
  for (int i = t; i < n; i += 256) atomicAdd(&cnt[pairs[s0 + i] >> 18], 1);
  __syncthreads();
  int d0 = b << 9;
#pragma unroll
  for (int j = 0; j < 2; ++j) {
    int dd = d0 + t + j * 256;
    if (dd < ndst) deg[dd] = cnt[t + j * 256];
  }
}

__global__ __launch_bounds__(256) void csr_scan_local(
    const int* __restrict__ deg1, const int* __restrict__ deg2,
    int* __restrict__ R1, int* __restrict__ R2,
    int* __restrict__ part1, int* __restrict__ part2) {
  __shared__ int sm[256];
  int b = blockIdx.x, t = threadIdx.x;
  const int* deg; int* R; int* part; int N;
  if (b < NBK1) { deg = deg1; R = R1; part = part1; N = CN1; }
  else { b -= NBK1; deg = deg2; R = R2; part = part2; N = CN2; }
  int base = b * 512;
  int i0 = base + 2 * t, i1 = base + 2 * t + 1;
  int a = (i0 < N) ? deg[i0] : 0;
  int bb = (i1 < N) ? deg[i1] : 0;
  int s = a + bb;
  sm[t] = s;
  __syncthreads();
#pragma unroll
  for (int off = 1; off < 256; off <<= 1) {
    int v = (t >= off) ? sm[t - off] : 0;
    __syncthreads();
    sm[t] += v;
    __syncthreads();
  }
  int excl = sm[t] - s;
  if (i0 < N) R[i0] = excl;
  if (i1 < N) R[i1] = excl + a;
  if (t == 255) part[b] = sm[255];
}

__global__ __launch_bounds__(256) void csr_scan_part(
    int* __restrict__ part1, int* __restrict__ part2) {
  __shared__ int sm[256];
  int t = threadIdx.x;
  int* part; int B;
  if (blockIdx.x == 0) { part = part1; B = NBK1; }
  else { part = part2; B = NBK2; }
  int v = (t < B) ? part[t] : 0;
  sm[t] = v;
  __syncthreads();
#pragma unroll
  for (int off = 1; off < 256; off <<= 1) {
    int u = (t >= off) ? sm[t - off] : 0;
    __syncthreads();
    sm[t] += u;
    __syncthreads();
  }
  if (t < B) part[t] = sm[t] - v;
}

// bplace with addback folded in: final offset = R[dd] + part[bucket]
__global__ __launch_bounds__(256) void csr_bplace(
    const uint32_t* __restrict__ pairs1, const uint32_t* __restrict__ pairs2,
    const int* __restrict__ Bb1, const int* __restrict__ Bb2,
    const int* __restrict__ T1, const int* __restrict__ T2,
    const int* __restrict__ R1, const int* __restrict__ R2,
    const int* __restrict__ part1, const int* __restrict__ part2,
    int* __restrict__ esrc1, int* __restrict__ esrc2) {
  __shared__ int curs[512];
  int b = blockIdx.x, t = threadIdx.x;
  const uint32_t* pairs; const int* Bb; const int* T; const int* R;
  const int* part; int* esrc; int ndst;
  if (b < NBK1) { pairs = pairs1; Bb = Bb1; T = T1; R = R1; part = part1;
                  esrc = esrc1; ndst = CN1; }
  else { b -= NBK1; pairs = pairs2; Bb = Bb2; T = T2; R = R2; part = part2;
         esrc = esrc2; ndst = CN2; }
  int d0 = b << 9;
  int pb = part[b];
#pragma unroll
  for (int j = 0; j < 2; ++j) {
    int dd = d0 + t + j * 256;
    curs[t + j * 256] = (dd < ndst) ? R[dd] + pb : 0;
  }
  __syncthreads();
  int s0 = Bb[b], n = T[b];
  for (int i = t; i < n; i += 256) {
    uint32_t pk = pairs[s0 + i];
    int p = atomicAdd(&curs[pk >> 18], 1);
    esrc[p] = (int)(pk & 0x3FFFFu);
  }
}

// ---------------- gather-mean (bf16 in), layer 1: 64 lanes/dst ----------------
__global__ __launch_bounds__(256) void sage_gather1(
    const uint16_t* __restrict__ xbf, const int* __restrict__ esrc,
    const int* __restrict__ R, const int* __restrict__ part,
    const int* __restrict__ deg, uint16_t* __restrict__ agg) {
  int d = blockIdx.x * 4 + (threadIdx.x >> 6);
  int c = threadIdx.x & 63;
  if (d >= CN1) return;
  int start = R[d] + part[d >> 9], n = deg[d];
  const uint32_t* xw = reinterpret_cast<const uint32_t*>(xbf);
  float a0 = 0.f, a1 = 0.f;
  int i = 0;
  for (; i + 4 <= n; i += 4) {
    int s0 = esrc[start + i + 0];
    int s1 = esrc[start + i + 1];
    int s2 = esrc[start + i + 2];
    int s3 = esrc[start + i + 3];
    uint32_t v0 = xw[(size_t)s0 * 64 + c];
    uint32_t v1 = xw[(size_t)s1 * 64 + c];
    uint32_t v2 = xw[(size_t)s2 * 64 + c];
    uint32_t v3 = xw[(size_t)s3 * 64 + c];
    a0 += __uint_as_float(v0 << 16) + __uint_as_float(v1 << 16) +
          __uint_as_float(v2 << 16) + __uint_as_float(v3 << 16);
    a1 += __uint_as_float(v0 & 0xffff0000u) + __uint_as_float(v1 & 0xffff0000u) +
          __uint_as_float(v2 & 0xffff0000u) + __uint_as_float(v3 & 0xffff0000u);
  }
  for (; i < n; ++i) {
    uint32_t v = xw[(size_t)esrc[start + i] * 64 + c];
    a0 += __uint_as_float(v << 16);
    a1 += __uint_as_float(v & 0xffff0000u);
  }
  float inv = 1.0f / fmaxf((float)n, 1.0f);
  a0 *= inv; a1 *= inv;
  uint32_t packed = (uint32_t)f2bf(a0) | ((uint32_t)f2bf(a1) << 16);
  reinterpret_cast<uint32_t*>(agg)[(size_t)d * 64 + c] = packed;
}

// ---------------- gather-mean (bf16 in), layer 2: 32 lanes/dst, f32 out ----
__global__ __launch_bounds__(256) void sage_gather2(
    const uint16_t* __restrict__ t2, const int* __restrict__ esrc,
    const int* __restrict__ R, const int* __restrict__ part,
    const int* __restrict__ deg, float* __restrict__ agg) {
  int d = blockIdx.x * 8 + (threadIdx.x >> 5);
  int c = threadIdx.x & 31;
  if (d >= CN2) return;
  int start = R[d] + part[d >> 9], n = deg[d];
  const uint32_t* tw = reinterpret_cast<const uint32_t*>(t2);
  float a0 = 0.f, a1 = 0.f;
  int i = 0;
  for (; i + 4 <= n; i += 4) {
    int s0 = esrc[start + i + 0];
    int s1 = esrc[start + i + 1];
    int s2 = esrc[start + i + 2];
    int s3 = esrc[start + i + 3];
    uint32_t v0 = tw[(size_t)s0 * 32 + c];
    uint32_t v1 = tw[(size_t)s1 * 32 + c];
    uint32_t v2 = tw[(size_t)s2 * 32 + c];
    uint32_t v3 = tw[(size_t)s3 * 32 + c];
    a0 += __uint_as_float(v0 << 16) + __uint_as_float(v1 << 16) +
          __uint_as_float(v2 << 16) + __uint_as_float(v3 << 16);
    a1 += __uint_as_float(v0 & 0xffff0000u) + __uint_as_float(v1 & 0xffff0000u) +
          __uint_as_float(v2 & 0xffff0000u) + __uint_as_float(v3 & 0xffff0000u);
  }
  for (; i < n; ++i) {
    uint32_t v = tw[(size_t)esrc[start + i] * 32 + c];
    a0 += __uint_as_float(v << 16);
    a1 += __uint_as_float(v & 0xffff0000u);
  }
  float inv = 1.0f / fmaxf((float)n, 1.0f);
  float2 o = {a0 * inv, a1 * inv};
  reinterpret_cast<float2*>(agg)[(size_t)d * 32 + c] = o;
}

// ---------------- MEGA kernel (R9: 2-phase register prefetch) ----------------
// Per 64-row block (4 waves; wave w owns rows w*16..w*16+15):
//   phase 1 (unrolled ht=0..7; h=ht>>2 col-half, t=ht&3 K-tile):
//     {sync; LDS<-regs; sync; prefetch regs(ht+1); MFMA(ht); [epilogue at t==3]}
//   phase 2: same shape over w2cat tiles; acc2 -> t2 | out partial.
//   epilogue: stage tiles in LDS (h1s dead), coalesced int4 stores.
__global__ __launch_bounds__(256, 2) void sage_mega(
    const uint16_t* __restrict__ agg, const uint16_t* __restrict__ xbf,
    const uint16_t* __restrict__ wcat, const uint16_t* __restrict__ w2cat,
    const float* __restrict__ bias, uint16_t* __restrict__ t2,
    float* __restrict__ outp) {
  __shared__ uint16_t lds[30720];  // 60 KB
  uint16_t* As  = lds;             // [64][72]
  uint16_t* Ws  = lds + 4608;      // [128][72]
  uint16_t* h1s = lds + 13824;     // [64][264]; epilogue: t2s+outs (24 KB)

  const int tid = threadIdx.x;
  const int w = tid >> 6;
  const int lane = tid & 63;
  const int lr = lane >> 4;
  const int lc = lane & 15;
  const int row0 = blockIdx.x * 64;

  // bias preload (16 VGPR): bv[h*8+n] = bias[h*128 + n*16 + lc]
  float bv[16];
#pragma unroll
  for (int j = 0; j < 16; ++j) bv[j] = bias[(j >> 3) * 128 + (j & 7) * 16 + lc];

  f32x4 acc[8];
#pragma unroll
  for (int n = 0; n < 8; ++n) acc[n] = (f32x4)0.0f;

  int4 av[2], wv[4];
  // prologue: load tile ht=0 (h=0, t=0: Asrc=agg, koff=0, k0=0)
#pragma unroll
  for (int i = 0; i < 2; ++i) {
    int q = tid + 256 * i;
    int r = q >> 3, c = q & 7;
    int rg = row0 + r;
    rg = rg < CN1 ? rg : CN1 - 1;
    av[i] = *reinterpret_cast<const int4*>(agg + (size_t)rg * CD_IN + c * 8);
  }
#pragma unroll
  for (int i = 0; i < 4; ++i) {
    int q = tid + 256 * i;
    int r = q >> 3, c = q & 7;
    wv[i] = *reinterpret_cast<const int4*>(wcat + (size_t)r * 256 + c * 8);
  }

#pragma unroll
  for (int ht = 0; ht < 8; ++ht) {
    const int h = ht >> 2, t = ht & 3;
    __syncthreads();   // prior MFMA reads of As/Ws complete
#pragma unroll
    for (int i = 0; i < 2; ++i) {
      int q = tid + 256 * i;
      int r = q >> 3, c = q & 7;
      *reinterpret_cast<int4*>(&As[r * 72 + c * 8]) = av[i];
    }
#pragma unroll
    for (int i = 0; i < 4; ++i) {
      int q = tid + 256 * i;
      int r = q >> 3, c = q & 7;
      *reinterpret_cast<int4*>(&Ws[r * 72 + c * 8]) = wv[i];
    }
    __syncthreads();

    // prefetch next tile's regs (overlaps the MFMA below)
    if (ht < 7) {
      const int h2 = (ht + 1) >> 2, t2i = (ht + 1) & 3;
      const uint16_t* Asrc = (t2i < 2) ? agg : xbf;
      const int koff = (t2i < 2) ? t2i * 64 : t2i * 64 - 128;
      const int k0n = t2i * 64;
#pragma unroll
      for (int i = 0; i < 2; ++i) {
        int q = tid + 256 * i;
        int r = q >> 3, c = q & 7;
        int rg = row0 + r;
        rg = rg < CN1 ? rg : CN1 - 1;
        av[i] = *reinterpret_cast<const int4*>(Asrc + (size_t)rg * CD_IN + koff + c * 8);
      }
#pragma unroll
      for (int i = 0; i < 4; ++i) {
        int q = tid + 256 * i;
        int r = q >> 3, c = q & 7;
        wv[i] = *reinterpret_cast<const int4*>(wcat + (size_t)(h2 * 128 + r) * 256 + k0n + c * 8);
      }
    }

    __builtin_amdgcn_s_setprio(1);
#pragma unroll
    for (int ks = 0; ks < 2; ++ks) {
      const int kb = ks * 32 + lr * 8;
      bf16x8 af = *reinterpret_cast<const bf16x8*>(&As[(w * 16 + lc) * 72 + kb]);
#pragma unroll
      for (int n = 0; n < 8; ++n) {
        bf16x8 bfv = *reinterpret_cast<const bf16x8*>(&Ws[(n * 16 + lc) * 72 + kb]);
        acc[n] = __builtin_amdgcn_mfma_f32_16x16x32_bf16(af, bfv, acc[n], 0, 0, 0);
      }
    }
    __builtin_amdgcn_s_setprio(0);

    if (t == 3) {
      // epilogue for col-half h: bias + relu -> bf16 -> h1s
#pragma unroll
      for (int n = 0; n < 8; ++n) {
#pragma unroll
        for (int i = 0; i < 4; ++i) {
          float v = fmaxf(acc[n][i] + bv[h * 8 + n], 0.0f);
          h1s[(w * 16 + lr * 4 + i) * 264 + h * 128 + n * 16 + lc] = f2bf(v);
        }
      }
#pragma unroll
      for (int n = 0; n < 8; ++n) acc[n] = (f32x4)0.0f;
    }
  }

  // ---- phase 2: [t2 | out_part] = h1 @ W2cat^T ----
  f32x4 acc2[8];
#pragma unroll
  for (int n = 0; n < 8; ++n) acc2[n] = (f32x4)0.0f;

  int4 w2v[4];
#pragma unroll
  for (int i = 0; i < 4; ++i) {
    int q = tid + 256 * i;
    int r = q >> 3, c = q & 7;
    w2v[i] = *reinterpret_cast<const int4*>(w2cat + (size_t)r * 256 + c * 8);
  }

#pragma unroll
  for (int t = 0; t < 4; ++t) {
    __syncthreads();   // h1s complete (t=0) / prior MFMA reads of Ws done
#pragma unroll
    for (int i = 0; i < 4; ++i) {
      int q = tid + 256 * i;
      int r = q >> 3, c = q & 7;
      *reinterpret_cast<int4*>(&Ws[r * 72 + c * 8]) = w2v[i];
    }
    __syncthreads();
    if (t < 3) {
      const int k0n = (t + 1) * 64;
#pragma unroll
      for (int i = 0; i < 4; ++i) {
        int q = tid + 256 * i;
        int r = q >> 3, c = q & 7;
        w2v[i] = *reinterpret_cast<const int4*>(w2cat + (size_t)r * 256 + k0n + c * 8);
      }
    }
    const int k0 = t * 64;
    __builtin_amdgcn_s_setprio(1);
#pragma unroll
    for (int ks = 0; ks < 2; ++ks) {
      const int kb = ks * 32 + lr * 8;
      bf16x8 af = *reinterpret_cast<const bf16x8*>(&h1s[(w * 16 + lc) * 264 + k0 + kb]);
#pragma unroll
      for (int n = 0; n < 8; ++n) {
        bf16x8 bfv = *reinterpret_cast<const bf16x8*>(&Ws[(n * 16 + lc) * 72 + kb]);
        acc2[n] = __builtin_amdgcn_mfma_f32_16x16x32_bf16(af, bfv, acc2[n], 0, 0, 0);
      }
    }
    __builtin_amdgcn_s_setprio(0);
  }

  // ---- epilogue 2: LDS-stage output tiles, then coalesced stores ----
  __syncthreads();
  uint16_t* t2s = h1s;                    // [64][64] u16 (8 KB)
  float* outs = (float*)(h1s + 4096);     // [64][64] f32 (16 KB)
#pragma unroll
  for (int i = 0; i < 4; ++i) {
    int rl = w * 16 + lr * 4 + i;
#pragma unroll
    for (int n = 0; n < 4; ++n) t2s[rl * 64 + n * 16 + lc] = f2bf(acc2[n][i]);
#pragma unroll
    for (int n = 0; n < 4; ++n) outs[rl * 64 + n * 16 + lc] = acc2[n + 4][i];
  }
  __syncthreads();
#pragma unroll
  for (int i = 0; i < 2; ++i) {
    int q = tid + 256 * i;
    int r = q >> 3, c = q & 7;
    int rg = row0 + r;
    if (rg < CN1)
      reinterpret_cast<int4*>(t2 + (size_t)rg * 64)[c] =
          *reinterpret_cast<const int4*>(&t2s[r * 64 + c * 8]);
  }
  if (row0 < CN2) {
#pragma unroll
    for (int i = 0; i < 4; ++i) {
      int q = tid + 256 * i;
      int r = q >> 4, c = q & 15;
      int rg = row0 + r;
      if (rg < CN2)
        reinterpret_cast<int4*>(outp + (size_t)rg * 64)[c] =
            *reinterpret_cast<const int4*>(&outs[r * 64 + c * 4]);
    }
  }
}

// ---------------- finalize: out = log_softmax(out + agg2 + b2) ----------------
__global__ __launch_bounds__(256) void sage_finalize(
    const float* __restrict__ agg2, const float* __restrict__ b,
    float* __restrict__ out) {
  int row = blockIdx.x * 4 + (threadIdx.x >> 6);
  int lane = threadIdx.x & 63;
  if (row >= CN2) return;
  size_t o = (size_t)row * CD_OUT + lane;
  float v = out[o] + agg2[o] + b[lane];
  float m = v;
#pragma unroll
  for (int d = 32; d > 0; d >>= 1) m = fmaxf(m, __shfl_xor(m, d));
  float e = expf(v - m);
  float s = e;
#pragma unroll
  for (int d = 32; d > 0; d >>= 1) s += __shfl_xor(s, d);
  out[o] = v - m - logf(s);
}

extern "C" void kernel_launch(void* const* d_in, const int* in_sizes, int n_in,
                              void* d_out, int out_size, void* d_ws, size_t ws_size,
                              hipStream_t stream) {
  const float* x    = (const float*)d_in[0];
  const int* src1   = (const int*)d_in[1];
  const int* dst1   = (const int*)d_in[2];
  const int* src2   = (const int*)d_in[3];
  const int* dst2   = (const int*)d_in[4];
  const float* W_l1 = (const float*)d_in[5];
  const float* b_l1 = (const float*)d_in[6];
  const float* W_r1 = (const float*)d_in[7];
  const float* W_l2 = (const float*)d_in[8];
  const float* b_l2 = (const float*)d_in[9];
  const float* W_r2 = (const float*)d_in[10];
  float* out = (float*)d_out;
  char* base = (char*)d_ws;

  // ---- workspace layout (bytes), ~111.5 MB ----
  uint16_t* x_bf  = (uint16_t*)base;                       // 51.2 MB
  uint16_t* t2_bf = (uint16_t*)(base + 51200000);          // 12.8 MB
  uint32_t* pairs1= (uint32_t*)(base + 64000000);          // 6.4 MB (E1*4)
  uint32_t* pairs2= (uint32_t*)(base + 70400000);          // 1.28 MB (E2*4)
  uint16_t* agg_bf= (uint16_t*)(base + 71680000);          // 25.6 MB
  float* agg2     = (float*)(base + 97280000);             // 5.12 MB
  int* deg1 = (int*)(base + 102400000);                    // 400 KB
  int* R1   = (int*)(base + 102800000);                    // 400 KB
  int* esrc1= (int*)(base + 103200000);                    // 6.4 MB
  int* deg2 = (int*)(base + 109600000);                    // 80 KB
  int* R2   = (int*)(base + 109680000);                    // 80 KB
  int* esrc2= (int*)(base + 109760000);                    // 1.28 MB
  int* H1   = (int*)(base + 111040000);                    // 200,704 B (G1*NBK1*4)
  int* H2   = (int*)(base + 111240704);                    // 10,240 B  (G2*NBK2*4)
  char* misc = base + 111250944;
  int* T1  = (int*)(misc);                                 // 784 B
  int* Bb1 = (int*)(misc + 1024);
  int* T2  = (int*)(misc + 2048);
  int* Bb2 = (int*)(misc + 3072);
  int* part1 = (int*)(misc + 4096);
  int* part2 = (int*)(misc + 5120);
  uint16_t* wcat  = (uint16_t*)(misc + 6144);              // 128 KB
  uint16_t* w2cat = wcat + 65536;                          // 64 KB

  if (ws_size < 112000000u) return;

  // ---- converts (2 launches) ----
  cvt_f32_bf16_v4<<<(CN0 * CD_IN / 4 + 255) / 256, 256, 0, stream>>>(x, x_bf, CN0 * CD_IN / 4);
  cvt_weights<<<384, 256, 0, stream>>>(W_l1, W_r1, W_l2, W_r2, wcat, w2cat);

  // ---- dual-layer CSR build (8 launches) ----
  csr_count<<<G1 + G2, 256, 0, stream>>>(dst1, dst2, H1, H2);
  csr_scan<<<NBK1 + NBK2, 256, 0, stream>>>(H1, H2, T1, T2);
  csr_base<<<2, 256, 0, stream>>>(T1, T2, Bb1, Bb2);
  csr_place<<<G1 + G2, 256, 0, stream>>>(src1, dst1, src2, dst2, H1, H2,
                                         Bb1, Bb2, pairs1, pairs2);
  csr_bdeg<<<NBK1 + NBK2, 256, 0, stream>>>(pairs1, pairs2, Bb1, Bb2, T1, T2,
                                            deg1, deg2);
  csr_scan_local<<<NBK1 + NBK2, 256, 0, stream>>>(deg1, deg2, R1, R2, part1, part2);
  csr_scan_part<<<2, 256, 0, stream>>>(part1, part2);
  csr_bplace<<<NBK1 + NBK2, 256, 0, stream>>>(pairs1, pairs2, Bb1, Bb2, T1, T2,
                                              R1, R2, part1, part2, esrc1, esrc2);

  // ---- gather1 -> mega -> gather2 -> finalize ----
  sage_gather1<<<(CN1 + 3) / 4, 256, 0, stream>>>(x_bf, esrc1, R1, part1, deg1, agg_bf);
  sage_mega<<<(CN1 + 63) / 64, 256, 0, stream>>>(
      agg_bf, x_bf, wcat, w2cat, b_l1, t2_bf, out);
  sage_gather2<<<(CN2 + 7) / 8, 256, 0, stream>>>(t2_bf, esrc2, R2, part2, deg2, agg2);
  sage_finalize<<<(CN2 + 3) / 4, 256, 0, stream>>>(agg2, b_l2, out);
}